// Round 8
// baseline (254.799 us; speedup 1.0000x reference)
//
#include <hip/hip_runtime.h>

#define NB 16
#define NH 4
#define HD 128
#define HW 1024
#define CIN 512

typedef short s16x8 __attribute__((ext_vector_type(8)));
typedef short s16x4 __attribute__((ext_vector_type(4)));
typedef float f32x4 __attribute__((ext_vector_type(4)));

static __device__ __forceinline__ short f2bf(float f) {
    union { float f; unsigned u; } v; v.f = f;
    unsigned r = v.u + 0x7fffu + ((v.u >> 16) & 1u);   // round-to-nearest-even
    return (short)(r >> 16);
}

// async global->LDS DMA, 16B per lane. LDS dest is wave-uniform base + lane*16
// (linear); global src is per-lane (carries the XOR swizzle).
static __device__ __forceinline__ void gload16(const short* g, short* l) {
    __builtin_amdgcn_global_load_lds(
        (const __attribute__((address_space(1))) unsigned int*)g,
        (__attribute__((address_space(3))) unsigned int*)l, 16, 0, 0);
}

// ---------------------------------------------------------------------------
// prep: x[b][c][p] fp32 -> xT[b][p][c] bf16 (32x32 LDS tile transpose)
//       W[o][c]   fp32 -> Wb bf16 (elementwise)
// ---------------------------------------------------------------------------
__global__ __launch_bounds__(256) void prep_xw(
    const float* __restrict__ x, const float* __restrict__ w,
    short* __restrict__ xT, short* __restrict__ Wb)
{
    int blk = blockIdx.x;
    if (blk < NB * 16 * 32) {                  // 8192 transpose tiles
        int b = blk >> 9, rem = blk & 511;
        int ct = rem >> 5, pt = rem & 31;      // 16 c-tiles x 32 p-tiles
        __shared__ float tile[32][33];
        int tc = threadIdx.x >> 5;             // 0..7
        int tp = threadIdx.x & 31;             // 0..31
        const float* xb = x + ((size_t)b * CIN + ct * 32) * HW + pt * 32;
        #pragma unroll
        for (int i = 0; i < 4; i++)
            tile[tc + i * 8][tp] = xb[(size_t)(tc + i * 8) * HW + tp];
        __syncthreads();
        int p = threadIdx.x >> 3, cq = threadIdx.x & 7;
        short* xo = xT + ((size_t)b * HW + pt * 32 + p) * CIN + ct * 32 + cq * 4;
        s16x4 o4 = { f2bf(tile[cq * 4 + 0][p]), f2bf(tile[cq * 4 + 1][p]),
                     f2bf(tile[cq * 4 + 2][p]), f2bf(tile[cq * 4 + 3][p]) };
        *reinterpret_cast<s16x4*>(xo) = o4;
    } else {
        int wb = blk - NB * 16 * 32;           // 0..767, 1024 elems each
        size_t base = (size_t)wb * 1024 + threadIdx.x * 4;
        const float4 v = *reinterpret_cast<const float4*>(w + base);
        s16x4 o4 = { f2bf(v.x), f2bf(v.y), f2bf(v.z), f2bf(v.w) };
        *reinterpret_cast<s16x4*>(Wb + base) = o4;
    }
}

// ---------------------------------------------------------------------------
// qkv projection GEMM, BK=64, m97 structure: global_load_lds DMA staging
// (width 16), single-buffered LDS, 2 barriers per K-step. Content keeps the
// 16B-chunk XOR swizzle (phys = c ^ (row&7)) via PRE-SWIZZLED per-lane global
// source + linear LDS dest (m173 pattern) -> frag reads & epilogues unchanged.
//   s=0: Q = val * (128^-0.5 * log2e)   [p][d]
//   s=1: K' = val + pos_h + pos_w       [p][d]
//   s=2: Vt = val                       [d][p]  -- p PERMUTED within 32-groups
//        (slot = 8*qs + 4*t + r  <-  u = 16*t + 4*qs + r), so attn's PV can
//        consume P directly from the S^T C-layout registers (no LDS trip).
// ---------------------------------------------------------------------------
__global__ __launch_bounds__(256, 3) void qkv_proj(
    const short* __restrict__ xT, const short* __restrict__ Wb,
    const float* __restrict__ pos_h, const float* __restrict__ pos_w,
    short* __restrict__ Q, short* __restrict__ Kp, short* __restrict__ Vt)
{
    __shared__ __align__(1024) char smem[34816];
    short* As = (short*)smem;               // [128][64] content-swizzled
    short* Bs = As + 128 * 64;              // [128][64] content-swizzled
    short* vb = (short*)smem;               // [128][136] reused for V epilogue

    const int pt = blockIdx.x, ot = blockIdx.y, b = blockIdx.z;
    const int tid = threadIdx.x;
    const int wave = tid >> 6, lane = tid & 63;
    const int l16 = lane & 15, quad = lane >> 4;
    const int wm = (wave & 1) * 64, wn = (wave >> 1) * 64;
    const int o0 = ot * 128, p0 = pt * 128;

    const short* xb = xT + (size_t)b * HW * CIN;

    // DMA staging geometry: wave w covers rows [w*32, w*32+32); instr j covers
    // 8 rows (1024 B). Lane: row_local = j*8 + (lane>>3), phys chunk = lane&7.
    // Source chunk = phys ^ (row&7); row&7 == lane>>3 (j*8, w*32 are 0 mod 8).
    const int r8 = lane >> 3, c8 = lane & 7;
    const int sch = c8 ^ r8;                  // pre-swizzled source chunk
    const short* wsrc = Wb + (size_t)(o0 + wave * 32 + r8) * CIN + sch * 8;
    const short* xsrc = xb + (size_t)(p0 + wave * 32 + r8) * CIN + sch * 8;
    short* adst = As + wave * 2048;           // + j*512 shorts (= j*1024 B)
    short* bdst = Bs + wave * 2048;

    f32x4 acc[4][4];
    #pragma unroll
    for (int i = 0; i < 4; i++)
        #pragma unroll
        for (int j = 0; j < 4; j++)
            acc[i][j] = f32x4{0.f, 0.f, 0.f, 0.f};

    #pragma unroll 1
    for (int kc = 0; kc < CIN; kc += 64) {
        #pragma unroll
        for (int j = 0; j < 4; j++) {
            gload16(wsrc + kc + (size_t)(j * 8) * CIN, adst + j * 512);
            gload16(xsrc + kc + (size_t)(j * 8) * CIN, bdst + j * 512);
        }
        __syncthreads();   // compiler drains vmcnt(0) before barrier
        #pragma unroll
        for (int kk = 0; kk < 2; kk++) {
            s16x8 aF[4], bF[4];
            #pragma unroll
            for (int mi = 0; mi < 4; mi++)
                aF[mi] = *(const s16x8*)(As + (wm + mi * 16 + l16) * 64
                                         + (((kk * 4 + quad) ^ (l16 & 7)) * 8));
            #pragma unroll
            for (int ni = 0; ni < 4; ni++)
                bF[ni] = *(const s16x8*)(Bs + (wn + ni * 16 + l16) * 64
                                         + (((kk * 4 + quad) ^ (l16 & 7)) * 8));
            #pragma unroll
            for (int mi = 0; mi < 4; mi++)
                #pragma unroll
                for (int ni = 0; ni < 4; ni++)
                    acc[mi][ni] = __builtin_amdgcn_mfma_f32_16x16x32_bf16(
                        aF[mi], bF[ni], acc[mi][ni], 0, 0, 0);
        }
        __syncthreads();   // all reads done before next DMA overwrites
    }

    const int s = ot >> 2, h = ot & 3;
    const size_t bh = (size_t)(b * NH + h);

    if (s == 0) {
        const float qs = 0.08838834764831845f * 1.4426950408889634f; // scale*log2e
        short* Qb = Q + bh * (size_t)(HW * HD);
        #pragma unroll
        for (int mi = 0; mi < 4; mi++) {
            int d0 = wm + mi * 16 + quad * 4;
            #pragma unroll
            for (int ni = 0; ni < 4; ni++) {
                int p = p0 + wn + ni * 16 + l16;
                f32x4 a = acc[mi][ni];
                s16x4 o4 = { f2bf(a.x * qs), f2bf(a.y * qs),
                             f2bf(a.z * qs), f2bf(a.w * qs) };
                *reinterpret_cast<s16x4*>(Qb + (size_t)p * HD + d0) = o4;
            }
        }
    } else if (s == 1) {
        short* Kb = Kp + bh * (size_t)(HW * HD);
        #pragma unroll
        for (int mi = 0; mi < 4; mi++) {
            int d0 = wm + mi * 16 + quad * 4;
            #pragma unroll
            for (int ni = 0; ni < 4; ni++) {
                int p = p0 + wn + ni * 16 + l16;
                const float4 eh = *reinterpret_cast<const float4*>(pos_h + (p >> 5) * HD + d0);
                const float4 ew = *reinterpret_cast<const float4*>(pos_w + (p & 31) * HD + d0);
                f32x4 a = acc[mi][ni];
                s16x4 o4 = { f2bf(a.x + eh.x + ew.x), f2bf(a.y + eh.y + ew.y),
                             f2bf(a.z + eh.z + ew.z), f2bf(a.w + eh.w + ew.w) };
                *reinterpret_cast<s16x4*>(Kb + (size_t)p * HD + d0) = o4;
            }
        }
    } else {
        __syncthreads();   // done with As/Bs before vb overlay
        #pragma unroll
        for (int mi = 0; mi < 4; mi++) {
            int d0 = wm + mi * 16 + quad * 4;
            #pragma unroll
            for (int ni = 0; ni < 4; ni++) {
                int p = wn + ni * 16 + l16;
                f32x4 a = acc[mi][ni];
                vb[(d0 + 0) * 136 + p] = f2bf(a.x);
                vb[(d0 + 1) * 136 + p] = f2bf(a.y);
                vb[(d0 + 2) * 136 + p] = f2bf(a.z);
                vb[(d0 + 3) * 136 + p] = f2bf(a.w);
            }
        }
        __syncthreads();
        short* Vb = Vt + bh * (size_t)(HD * HW);
        int d = tid >> 1, half = tid & 1;
        // key-permuted store: out slot group g=(half*2+(j>>2)), qs=(j&3):
        //   slots 8qs..8qs+3 (t=0) <- u = g*32 + 4qs + r
        //   slots 8qs+4..+7 (t=1) <- u = g*32 + 16 + 4qs + r
        #pragma unroll
        for (int j = 0; j < 8; j++) {
            const short* row = vb + d * 136;
            int base = (half * 2 + (j >> 2)) * 32 + (j & 3) * 4;
            s16x4 lo = *(const s16x4*)(row + base);
            s16x4 hi = *(const s16x4*)(row + base + 16);
            s16x8 v8 = { lo[0], lo[1], lo[2], lo[3],
                         hi[0], hi[1], hi[2], hi[3] };
            *reinterpret_cast<s16x8*>(Vb + (size_t)d * HW + p0 + half * 64 + j * 8) = v8;
        }
    }
}

// ---------------------------------------------------------------------------
// Fused attention R8: NO LDS AT ALL (m169 play). KV per head = 512KB bf16,
// L2-resident on one XCD (XCD-affine bh: all 8 q-tile blocks of a head land
// on the same XCD; 8 bh/XCD x hot region << 4MB L2). K/V fragments are read
// DIRECTLY from global (L1/L2-served); the staging XOR algebra cancels to:
//   aK[mtp][kk] = Kb[(kt*64+mtp*16+l16)*128 + (kk*4+quad)*8]
//   bV[h][dt]   = Vb[(dt*16+l16)*HW + kt*64 + (h*4+quad)*8]
// Removes: DMA staging, 32 b128 LDS reads/wave-iter, ALL barriers -> the 4
// waves are fully independent (no race surface), free-running for latency
// hiding; compiler may pipeline loads across iters. setprio kept (m191:
// helps when waves are at different phases -- now always true).
// P never touches LDS (R3): V stored key-PERMUTED (qkv_proj) so S^T C-layout
// regs are directly PV's A-frags. Grid 512, 2 blocks/CU (grid-limited).
// ---------------------------------------------------------------------------
__global__ __launch_bounds__(256, 2) void attn_fused(
    const short* __restrict__ Q, const short* __restrict__ Kp,
    const short* __restrict__ Vt, float* __restrict__ out)
{
    const int flat = blockIdx.x;
    const int qt = flat >> 6;              // 0..7
    const int bh = flat & 63;              // XCD-affine: bh%8 == blockIdx%8
    const int tid = threadIdx.x;
    const int wave = tid >> 6, lane = tid & 63;
    const int l16 = lane & 15, quad = lane >> 4;

    const short* Qb = Q + (size_t)bh * (HW * HD);
    const short* Kb = Kp + (size_t)bh * (HW * HD);
    const short* Vb = Vt + (size_t)bh * (HD * HW);

    const int q0 = qt * 128 + wave * 32;

    // Q fragments (B-operand for S^T): this wave's 32 rows, K=128 -> 2x4 frags
    s16x8 bQ[2][4];
    #pragma unroll
    for (int nt = 0; nt < 2; nt++)
        #pragma unroll
        for (int kk = 0; kk < 4; kk++)
            bQ[nt][kk] = *(const s16x8*)(Qb + (size_t)(q0 + nt * 16 + l16) * HD
                                         + kk * 32 + quad * 8);

    s16x8 ones;
    #pragma unroll
    for (int j = 0; j < 8; j++) ones[j] = (short)0x3F80;   // bf16 1.0

    f32x4 Oacc[2][8];
    #pragma unroll
    for (int mt = 0; mt < 2; mt++)
        #pragma unroll
        for (int dt = 0; dt < 8; dt++)
            Oacc[mt][dt] = f32x4{0.f, 0.f, 0.f, 0.f};
    f32x4 lacc[2] = { f32x4{0.f, 0.f, 0.f, 0.f}, f32x4{0.f, 0.f, 0.f, 0.f} };

    // per-lane bases for direct K/V fragment loads
    const short* kbase = Kb + l16 * HD + quad * 8;
    const short* vbase = Vb + (size_t)l16 * HW + quad * 8;

    #pragma unroll 1
    for (int kt = 0; kt < 16; kt++) {
        // ---- K frags for this 64-key tile (L1/L2-served; 16 b128 loads)
        s16x8 aK[4][4];
        #pragma unroll
        for (int mtp = 0; mtp < 4; mtp++)
            #pragma unroll
            for (int kk = 0; kk < 4; kk++)
                aK[mtp][kk] = *(const s16x8*)(kbase
                    + (size_t)(kt * 64 + mtp * 16) * HD + kk * 32);

        // ---- S^T: 64 keys x 32 qrows (aK shared across both q-tiles)
        f32x4 c[4][2];
        __builtin_amdgcn_s_setprio(1);
        #pragma unroll
        for (int mtp = 0; mtp < 4; mtp++) {
            c[mtp][0] = f32x4{0.f, 0.f, 0.f, 0.f};
            c[mtp][1] = f32x4{0.f, 0.f, 0.f, 0.f};
            #pragma unroll
            for (int kk = 0; kk < 4; kk++) {
                c[mtp][0] = __builtin_amdgcn_mfma_f32_16x16x32_bf16(
                    aK[mtp][kk], bQ[0][kk], c[mtp][0], 0, 0, 0);
                c[mtp][1] = __builtin_amdgcn_mfma_f32_16x16x32_bf16(
                    aK[mtp][kk], bQ[1][kk], c[mtp][1], 0, 0, 0);
            }
        }
        __builtin_amdgcn_s_setprio(0);

        // ---- V frags (no P dependence; loads overlap the exp2 phase)
        s16x8 bV[2][8];
        #pragma unroll
        for (int h2 = 0; h2 < 2; h2++)
            #pragma unroll
            for (int dt = 0; dt < 8; dt++)
                bV[h2][dt] = *(const s16x8*)(vbase
                    + (size_t)(dt * 16) * HW + kt * 64 + h2 * 32);

        // ---- P = exp2(S') packed ENTIRELY in registers (V rows permuted to
        //      match the C-layout keys each lane holds). Two 32-key halves.
        #pragma unroll
        for (int h = 0; h < 2; h++) {
            s16x8 aP[2];
            #pragma unroll
            for (int mt = 0; mt < 2; mt++) {
                f32x4 e0 = c[2 * h][mt], e1 = c[2 * h + 1][mt];
                aP[mt] = s16x8{
                    f2bf(__builtin_amdgcn_exp2f(e0[0])),
                    f2bf(__builtin_amdgcn_exp2f(e0[1])),
                    f2bf(__builtin_amdgcn_exp2f(e0[2])),
                    f2bf(__builtin_amdgcn_exp2f(e0[3])),
                    f2bf(__builtin_amdgcn_exp2f(e1[0])),
                    f2bf(__builtin_amdgcn_exp2f(e1[1])),
                    f2bf(__builtin_amdgcn_exp2f(e1[2])),
                    f2bf(__builtin_amdgcn_exp2f(e1[3])) };
            }

            __builtin_amdgcn_s_setprio(1);
            #pragma unroll
            for (int mt = 0; mt < 2; mt++)
                lacc[mt] = __builtin_amdgcn_mfma_f32_16x16x32_bf16(
                    aP[mt], ones, lacc[mt], 0, 0, 0);

            #pragma unroll
            for (int dt = 0; dt < 8; dt++) {
                #pragma unroll
                for (int mt = 0; mt < 2; mt++)
                    Oacc[mt][dt] = __builtin_amdgcn_mfma_f32_16x16x32_bf16(
                        aP[mt], bV[h][dt], Oacc[mt][dt], 0, 0, 0);
            }
            __builtin_amdgcn_s_setprio(0);
        }
    }

    // epilogue: O/l, stored transposed -> out[b][h][d][p] FP32
    float* ob = out + (size_t)bh * (HD * HW);
    #pragma unroll
    for (int mt = 0; mt < 2; mt++) {
        float inv[4];
        #pragma unroll
        for (int r = 0; r < 4; r++) inv[r] = __builtin_amdgcn_rcpf(lacc[mt][r]);
        int prow = q0 + mt * 16 + quad * 4;
        #pragma unroll
        for (int dt = 0; dt < 8; dt++) {
            int d = dt * 16 + l16;
            f32x4 o = Oacc[mt][dt];
            float4 o4 = { o[0] * inv[0], o[1] * inv[1],
                          o[2] * inv[2], o[3] * inv[3] };
            *reinterpret_cast<float4*>(ob + (size_t)d * HW + prow) = o4;
        }
    }
}

// ---------------------------------------------------------------------------
extern "C" void kernel_launch(void* const* d_in, const int* in_sizes, int n_in,
                              void* d_out, int out_size, void* d_ws, size_t ws_size,
                              hipStream_t stream) {
    const float* x  = (const float*)d_in[0];
    const float* w  = (const float*)d_in[1];
    const float* ph = (const float*)d_in[2];
    const float* pw = (const float*)d_in[3];

    const size_t BHPD = (size_t)NB * NH * HW * HD;   // 8,388,608 elems
    short* Q    = (short*)d_ws;
    short* Kp   = Q + BHPD;
    short* Vt   = Kp + BHPD;
    short* xT   = Vt + BHPD;
    short* Wb   = xT + (size_t)NB * HW * CIN;
    float* outp = (float*)d_out;

    prep_xw<<<dim3(NB * 16 * 32 + 768), 256, 0, stream>>>(x, w, xT, Wb);
    qkv_proj<<<dim3(8, 12, NB), 256, 0, stream>>>(xT, Wb, ph, pw, Q, Kp, Vt);
    attn_fused<<<dim3(512), 256, 0, stream>>>(Q, Kp, Vt, outp);
}

// Round 9
// 194.736 us; speedup vs baseline: 1.3084x; 1.3084x over previous
//
#include <hip/hip_runtime.h>

#define NB 16
#define NH 4
#define HD 128
#define HW 1024
#define CIN 512

typedef short s16x8 __attribute__((ext_vector_type(8)));
typedef short s16x4 __attribute__((ext_vector_type(4)));
typedef float f32x4 __attribute__((ext_vector_type(4)));

static __device__ __forceinline__ short f2bf(float f) {
    union { float f; unsigned u; } v; v.f = f;
    unsigned r = v.u + 0x7fffu + ((v.u >> 16) & 1u);   // round-to-nearest-even
    return (short)(r >> 16);
}

// async global->LDS DMA, 16B per lane. LDS dest is wave-uniform base + lane*16
// (linear); global src is per-lane (carries the XOR swizzle).
static __device__ __forceinline__ void gload16(const short* g, short* l) {
    __builtin_amdgcn_global_load_lds(
        (const __attribute__((address_space(1))) unsigned int*)g,
        (__attribute__((address_space(3))) unsigned int*)l, 16, 0, 0);
}

// ---------------------------------------------------------------------------
// prep: x[b][c][p] fp32 -> xT[b][p][c] bf16 (32x32 LDS tile transpose)
//       W[o][c]   fp32 -> Wb bf16 (elementwise)
// ---------------------------------------------------------------------------
__global__ __launch_bounds__(256) void prep_xw(
    const float* __restrict__ x, const float* __restrict__ w,
    short* __restrict__ xT, short* __restrict__ Wb)
{
    int blk = blockIdx.x;
    if (blk < NB * 16 * 32) {                  // 8192 transpose tiles
        int b = blk >> 9, rem = blk & 511;
        int ct = rem >> 5, pt = rem & 31;      // 16 c-tiles x 32 p-tiles
        __shared__ float tile[32][33];
        int tc = threadIdx.x >> 5;             // 0..7
        int tp = threadIdx.x & 31;             // 0..31
        const float* xb = x + ((size_t)b * CIN + ct * 32) * HW + pt * 32;
        #pragma unroll
        for (int i = 0; i < 4; i++)
            tile[tc + i * 8][tp] = xb[(size_t)(tc + i * 8) * HW + tp];
        __syncthreads();
        int p = threadIdx.x >> 3, cq = threadIdx.x & 7;
        short* xo = xT + ((size_t)b * HW + pt * 32 + p) * CIN + ct * 32 + cq * 4;
        s16x4 o4 = { f2bf(tile[cq * 4 + 0][p]), f2bf(tile[cq * 4 + 1][p]),
                     f2bf(tile[cq * 4 + 2][p]), f2bf(tile[cq * 4 + 3][p]) };
        *reinterpret_cast<s16x4*>(xo) = o4;
    } else {
        int wb = blk - NB * 16 * 32;           // 0..767, 1024 elems each
        size_t base = (size_t)wb * 1024 + threadIdx.x * 4;
        const float4 v = *reinterpret_cast<const float4*>(w + base);
        s16x4 o4 = { f2bf(v.x), f2bf(v.y), f2bf(v.z), f2bf(v.w) };
        *reinterpret_cast<s16x4*>(Wb + base) = o4;
    }
}

// ---------------------------------------------------------------------------
// qkv projection GEMM, BK=64, m97 structure: global_load_lds DMA staging
// (width 16), single-buffered LDS, 2 barriers per K-step. Content keeps the
// 16B-chunk XOR swizzle (phys = c ^ (row&7)) via PRE-SWIZZLED per-lane global
// source + linear LDS dest (m173 pattern) -> frag reads & epilogues unchanged.
//   s=0: Q = val * (128^-0.5 * log2e)   [p][d]
//   s=1: K' = val + pos_h + pos_w       [p][d]
//   s=2: Vt = val                       [d][p]  -- p PERMUTED within 32-groups
//        (slot = 8*qs + 4*t + r  <-  u = 16*t + 4*qs + r), so attn's PV can
//        consume P directly from the S^T C-layout registers (no LDS trip).
// ---------------------------------------------------------------------------
__global__ __launch_bounds__(256, 3) void qkv_proj(
    const short* __restrict__ xT, const short* __restrict__ Wb,
    const float* __restrict__ pos_h, const float* __restrict__ pos_w,
    short* __restrict__ Q, short* __restrict__ Kp, short* __restrict__ Vt)
{
    __shared__ __align__(1024) char smem[34816];
    short* As = (short*)smem;               // [128][64] content-swizzled
    short* Bs = As + 128 * 64;              // [128][64] content-swizzled
    short* vb = (short*)smem;               // [128][136] reused for V epilogue

    const int pt = blockIdx.x, ot = blockIdx.y, b = blockIdx.z;
    const int tid = threadIdx.x;
    const int wave = tid >> 6, lane = tid & 63;
    const int l16 = lane & 15, quad = lane >> 4;
    const int wm = (wave & 1) * 64, wn = (wave >> 1) * 64;
    const int o0 = ot * 128, p0 = pt * 128;

    const short* xb = xT + (size_t)b * HW * CIN;

    // DMA staging geometry: wave w covers rows [w*32, w*32+32); instr j covers
    // 8 rows (1024 B). Lane: row_local = j*8 + (lane>>3), phys chunk = lane&7.
    // Source chunk = phys ^ (row&7); row&7 == lane>>3 (j*8, w*32 are 0 mod 8).
    const int r8 = lane >> 3, c8 = lane & 7;
    const int sch = c8 ^ r8;                  // pre-swizzled source chunk
    const short* wsrc = Wb + (size_t)(o0 + wave * 32 + r8) * CIN + sch * 8;
    const short* xsrc = xb + (size_t)(p0 + wave * 32 + r8) * CIN + sch * 8;
    short* adst = As + wave * 2048;           // + j*512 shorts (= j*1024 B)
    short* bdst = Bs + wave * 2048;

    f32x4 acc[4][4];
    #pragma unroll
    for (int i = 0; i < 4; i++)
        #pragma unroll
        for (int j = 0; j < 4; j++)
            acc[i][j] = f32x4{0.f, 0.f, 0.f, 0.f};

    #pragma unroll 1
    for (int kc = 0; kc < CIN; kc += 64) {
        #pragma unroll
        for (int j = 0; j < 4; j++) {
            gload16(wsrc + kc + (size_t)(j * 8) * CIN, adst + j * 512);
            gload16(xsrc + kc + (size_t)(j * 8) * CIN, bdst + j * 512);
        }
        __syncthreads();   // compiler drains vmcnt(0) before barrier
        #pragma unroll
        for (int kk = 0; kk < 2; kk++) {
            s16x8 aF[4], bF[4];
            #pragma unroll
            for (int mi = 0; mi < 4; mi++)
                aF[mi] = *(const s16x8*)(As + (wm + mi * 16 + l16) * 64
                                         + (((kk * 4 + quad) ^ (l16 & 7)) * 8));
            #pragma unroll
            for (int ni = 0; ni < 4; ni++)
                bF[ni] = *(const s16x8*)(Bs + (wn + ni * 16 + l16) * 64
                                         + (((kk * 4 + quad) ^ (l16 & 7)) * 8));
            #pragma unroll
            for (int mi = 0; mi < 4; mi++)
                #pragma unroll
                for (int ni = 0; ni < 4; ni++)
                    acc[mi][ni] = __builtin_amdgcn_mfma_f32_16x16x32_bf16(
                        aF[mi], bF[ni], acc[mi][ni], 0, 0, 0);
        }
        __syncthreads();   // all reads done before next DMA overwrites
    }

    const int s = ot >> 2, h = ot & 3;
    const size_t bh = (size_t)(b * NH + h);

    if (s == 0) {
        const float qs = 0.08838834764831845f * 1.4426950408889634f; // scale*log2e
        short* Qb = Q + bh * (size_t)(HW * HD);
        #pragma unroll
        for (int mi = 0; mi < 4; mi++) {
            int d0 = wm + mi * 16 + quad * 4;
            #pragma unroll
            for (int ni = 0; ni < 4; ni++) {
                int p = p0 + wn + ni * 16 + l16;
                f32x4 a = acc[mi][ni];
                s16x4 o4 = { f2bf(a.x * qs), f2bf(a.y * qs),
                             f2bf(a.z * qs), f2bf(a.w * qs) };
                *reinterpret_cast<s16x4*>(Qb + (size_t)p * HD + d0) = o4;
            }
        }
    } else if (s == 1) {
        short* Kb = Kp + bh * (size_t)(HW * HD);
        #pragma unroll
        for (int mi = 0; mi < 4; mi++) {
            int d0 = wm + mi * 16 + quad * 4;
            #pragma unroll
            for (int ni = 0; ni < 4; ni++) {
                int p = p0 + wn + ni * 16 + l16;
                const float4 eh = *reinterpret_cast<const float4*>(pos_h + (p >> 5) * HD + d0);
                const float4 ew = *reinterpret_cast<const float4*>(pos_w + (p & 31) * HD + d0);
                f32x4 a = acc[mi][ni];
                s16x4 o4 = { f2bf(a.x + eh.x + ew.x), f2bf(a.y + eh.y + ew.y),
                             f2bf(a.z + eh.z + ew.z), f2bf(a.w + eh.w + ew.w) };
                *reinterpret_cast<s16x4*>(Kb + (size_t)p * HD + d0) = o4;
            }
        }
    } else {
        __syncthreads();   // done with As/Bs before vb overlay
        #pragma unroll
        for (int mi = 0; mi < 4; mi++) {
            int d0 = wm + mi * 16 + quad * 4;
            #pragma unroll
            for (int ni = 0; ni < 4; ni++) {
                int p = wn + ni * 16 + l16;
                f32x4 a = acc[mi][ni];
                vb[(d0 + 0) * 136 + p] = f2bf(a.x);
                vb[(d0 + 1) * 136 + p] = f2bf(a.y);
                vb[(d0 + 2) * 136 + p] = f2bf(a.z);
                vb[(d0 + 3) * 136 + p] = f2bf(a.w);
            }
        }
        __syncthreads();
        short* Vb = Vt + bh * (size_t)(HD * HW);
        int d = tid >> 1, half = tid & 1;
        // key-permuted store: out slot group g=(half*2+(j>>2)), qs=(j&3):
        //   slots 8qs..8qs+3 (t=0) <- u = g*32 + 4qs + r
        //   slots 8qs+4..+7 (t=1) <- u = g*32 + 16 + 4qs + r
        #pragma unroll
        for (int j = 0; j < 8; j++) {
            const short* row = vb + d * 136;
            int base = (half * 2 + (j >> 2)) * 32 + (j & 3) * 4;
            s16x4 lo = *(const s16x4*)(row + base);
            s16x4 hi = *(const s16x4*)(row + base + 16);
            s16x8 v8 = { lo[0], lo[1], lo[2], lo[3],
                         hi[0], hi[1], hi[2], hi[3] };
            *reinterpret_cast<s16x8*>(Vb + (size_t)d * HW + p0 + half * 64 + j * 8) = v8;
        }
    }
}

// ---------------------------------------------------------------------------
// Fused attention R9 (hybrid, m169 play): K DMA-staged + double-buffered in
// LDS (keeps the iteration-ahead prefetch R8 lost -> S^T never waits on
// global latency); V read DIRECT from global with its 16 b128 loads issued at
// the TOP of the iteration -- a full S^T MFMA cluster + exp2 phase (~1000cyc)
// covers ~200cyc L2 latency. R8's failure isolated the mechanism: direct
// loads feeding MFMA immediately (K) are latency-toxic at 8 waves/CU; loads
// with a long cover window (V) are not.
//   bV[h][dt] = Vb[(dt*16+l16)*HW + kt*64 + h*32 + quad*8]  (swizzle cancels)
// LDS halves 66->33KB; LDS issue/wave-iter: 32 reads+8 DMA -> 16 reads+4 DMA.
// P never touches LDS (R3): V stored key-PERMUTED (qkv_proj) so S^T C-layout
// regs are directly PV's A-frags. ONE barrier per iter. Grid 512, 2 blocks/CU.
// ---------------------------------------------------------------------------
__global__ __launch_bounds__(256, 2) void attn_fused(
    const short* __restrict__ Q, const short* __restrict__ Kp,
    const short* __restrict__ Vt, float* __restrict__ out)
{
    __shared__ __align__(1024) short Ks[2][64 * 128];   // [buf][key][d] swz: c^(key&15)

    const int flat = blockIdx.x;
    const int qt = flat >> 6;              // 0..7
    const int bh = flat & 63;              // XCD-affine: bh%8 == blockIdx%8
    const int tid = threadIdx.x;
    const int wave = tid >> 6, lane = tid & 63;
    const int l16 = lane & 15, quad = lane >> 4;

    const short* Qb = Q + (size_t)bh * (HW * HD);
    const short* Kb = Kp + (size_t)bh * (HW * HD);
    const short* Vb = Vt + (size_t)bh * (HD * HW);

    const int q0 = qt * 128 + wave * 32;

    // Q fragments (B-operand for S^T): this wave's 32 rows, K=128 -> 2x4 frags
    s16x8 bQ[2][4];
    #pragma unroll
    for (int nt = 0; nt < 2; nt++)
        #pragma unroll
        for (int kk = 0; kk < 4; kk++)
            bQ[nt][kk] = *(const s16x8*)(Qb + (size_t)(q0 + nt * 16 + l16) * HD
                                         + kk * 32 + quad * 8);

    s16x8 ones;
    #pragma unroll
    for (int j = 0; j < 8; j++) ones[j] = (short)0x3F80;   // bf16 1.0

    f32x4 Oacc[2][8];
    #pragma unroll
    for (int mt = 0; mt < 2; mt++)
        #pragma unroll
        for (int dt = 0; dt < 8; dt++)
            Oacc[mt][dt] = f32x4{0.f, 0.f, 0.f, 0.f};
    f32x4 lacc[2] = { f32x4{0.f, 0.f, 0.f, 0.f}, f32x4{0.f, 0.f, 0.f, 0.f} };

    // K DMA staging geometry (16 KB/tile = 16 instrs of 1KB; 4 per wave):
    // instr j: keys wave*16 + j*4 .. +4. lane: key = base + (lane>>4),
    //   phys chunk = lane&15, src chunk = (lane&15) ^ (key&15),
    //   key&15 = j*4 + (lane>>4)  (wave*16 == 0 mod 16).
    const int kRow = lane >> 4;            // 0..3

    // per-lane base for direct V fragment loads (global, L1/L2-served)
    const short* vbase = Vb + (size_t)l16 * HW + quad * 8;

    #define STAGE_K(buf, tile)                                                \
        do {                                                                  \
            _Pragma("unroll")                                                 \
            for (int j = 0; j < 4; j++) {                                     \
                int kkey = wave * 16 + j * 4 + kRow;                          \
                gload16(Kb + ((size_t)((tile) * 64 + kkey)) * HD              \
                           + (((lane & 15) ^ (j * 4 + kRow)) * 8),            \
                        &Ks[buf][(wave * 16 + j * 4) * 128] + lane * 8);      \
            }                                                                 \
        } while (0)

    STAGE_K(0, 0);         // tile 0 -> buf0 (vmcnt drained by barrier below)
    __syncthreads();

    #pragma unroll 1
    for (int kt = 0; kt < 16; kt++) {
        const int cur = kt & 1, nxt = cur ^ 1;
        const short* ks = Ks[cur];

        // issue K DMA for tile kt+1 into nxt (overlaps this iter's compute)
        STAGE_K(nxt, (kt + 1) & 15);   // wrap at end: harmless L2-hot reload

        // ---- issue V loads for THIS tile now: consumed only after S^T+exp2,
        //      so ~1000+ cyc of MFMA/VALU cover their L2 latency.
        s16x8 bV[2][8];
        #pragma unroll
        for (int h2 = 0; h2 < 2; h2++)
            #pragma unroll
            for (int dt = 0; dt < 8; dt++)
                bV[h2][dt] = *(const s16x8*)(vbase
                    + (size_t)(dt * 16) * HW + kt * 64 + h2 * 32);

        // ---- S^T: 64 keys x 32 qrows (aK shared across both q-tiles)
        f32x4 c[4][2];
        __builtin_amdgcn_s_setprio(1);
        #pragma unroll
        for (int mtp = 0; mtp < 4; mtp++) {
            s16x8 aK[4];
            #pragma unroll
            for (int kk = 0; kk < 4; kk++)
                aK[kk] = *(const s16x8*)(ks + (mtp * 16 + l16) * 128
                                         + (((kk * 4 + quad) ^ l16) * 8));
            c[mtp][0] = f32x4{0.f, 0.f, 0.f, 0.f};
            c[mtp][1] = f32x4{0.f, 0.f, 0.f, 0.f};
            #pragma unroll
            for (int kk = 0; kk < 4; kk++) {
                c[mtp][0] = __builtin_amdgcn_mfma_f32_16x16x32_bf16(
                    aK[kk], bQ[0][kk], c[mtp][0], 0, 0, 0);
                c[mtp][1] = __builtin_amdgcn_mfma_f32_16x16x32_bf16(
                    aK[kk], bQ[1][kk], c[mtp][1], 0, 0, 0);
            }
        }
        __builtin_amdgcn_s_setprio(0);

        // ---- P = exp2(S') packed ENTIRELY in registers (V rows permuted to
        //      match the C-layout keys each lane holds). Two 32-key halves.
        #pragma unroll
        for (int h = 0; h < 2; h++) {
            s16x8 aP[2];
            #pragma unroll
            for (int mt = 0; mt < 2; mt++) {
                f32x4 e0 = c[2 * h][mt], e1 = c[2 * h + 1][mt];
                aP[mt] = s16x8{
                    f2bf(__builtin_amdgcn_exp2f(e0[0])),
                    f2bf(__builtin_amdgcn_exp2f(e0[1])),
                    f2bf(__builtin_amdgcn_exp2f(e0[2])),
                    f2bf(__builtin_amdgcn_exp2f(e0[3])),
                    f2bf(__builtin_amdgcn_exp2f(e1[0])),
                    f2bf(__builtin_amdgcn_exp2f(e1[1])),
                    f2bf(__builtin_amdgcn_exp2f(e1[2])),
                    f2bf(__builtin_amdgcn_exp2f(e1[3])) };
            }

            __builtin_amdgcn_s_setprio(1);
            #pragma unroll
            for (int mt = 0; mt < 2; mt++)
                lacc[mt] = __builtin_amdgcn_mfma_f32_16x16x32_bf16(
                    aP[mt], ones, lacc[mt], 0, 0, 0);

            #pragma unroll
            for (int dt = 0; dt < 8; dt++) {
                #pragma unroll
                for (int mt = 0; mt < 2; mt++)
                    Oacc[mt][dt] = __builtin_amdgcn_mfma_f32_16x16x32_bf16(
                        aP[mt], bV[h][dt], Oacc[mt][dt], 0, 0, 0);
            }
            __builtin_amdgcn_s_setprio(0);
        }
        __syncthreads();   // drains K DMA (nxt ready) + orders cur reads
    }
    #undef STAGE_K

    // epilogue: O/l, stored transposed -> out[b][h][d][p] FP32
    float* ob = out + (size_t)bh * (HD * HW);
    #pragma unroll
    for (int mt = 0; mt < 2; mt++) {
        float inv[4];
        #pragma unroll
        for (int r = 0; r < 4; r++) inv[r] = __builtin_amdgcn_rcpf(lacc[mt][r]);
        int prow = q0 + mt * 16 + quad * 4;
        #pragma unroll
        for (int dt = 0; dt < 8; dt++) {
            int d = dt * 16 + l16;
            f32x4 o = Oacc[mt][dt];
            float4 o4 = { o[0] * inv[0], o[1] * inv[1],
                          o[2] * inv[2], o[3] * inv[3] };
            *reinterpret_cast<float4*>(ob + (size_t)d * HW + prow) = o4;
        }
    }
}

// ---------------------------------------------------------------------------
extern "C" void kernel_launch(void* const* d_in, const int* in_sizes, int n_in,
                              void* d_out, int out_size, void* d_ws, size_t ws_size,
                              hipStream_t stream) {
    const float* x  = (const float*)d_in[0];
    const float* w  = (const float*)d_in[1];
    const float* ph = (const float*)d_in[2];
    const float* pw = (const float*)d_in[3];

    const size_t BHPD = (size_t)NB * NH * HW * HD;   // 8,388,608 elems
    short* Q    = (short*)d_ws;
    short* Kp   = Q + BHPD;
    short* Vt   = Kp + BHPD;
    short* xT   = Vt + BHPD;
    short* Wb   = xT + (size_t)NB * HW * CIN;
    float* outp = (float*)d_out;

    prep_xw<<<dim3(NB * 16 * 32 + 768), 256, 0, stream>>>(x, w, xT, Wb);
    qkv_proj<<<dim3(8, 12, NB), 256, 0, stream>>>(xT, Wb, ph, pw, Q, Kp, Vt);
    attn_fused<<<dim3(512), 256, 0, stream>>>(Q, Kp, Vt, outp);
}

// Round 10
// 179.019 us; speedup vs baseline: 1.4233x; 1.0878x over previous
//
#include <hip/hip_runtime.h>

#define NB 16
#define NH 4
#define HD 128
#define HW 1024
#define CIN 512

typedef short s16x8 __attribute__((ext_vector_type(8)));
typedef short s16x4 __attribute__((ext_vector_type(4)));
typedef float f32x4 __attribute__((ext_vector_type(4)));

static __device__ __forceinline__ short f2bf(float f) {
    union { float f; unsigned u; } v; v.f = f;
    unsigned r = v.u + 0x7fffu + ((v.u >> 16) & 1u);   // round-to-nearest-even
    return (short)(r >> 16);
}

// async global->LDS DMA, 16B per lane. LDS dest is wave-uniform base + lane*16
// (linear); global src is per-lane (carries the XOR swizzle).
static __device__ __forceinline__ void gload16(const short* g, short* l) {
    __builtin_amdgcn_global_load_lds(
        (const __attribute__((address_space(1))) unsigned int*)g,
        (__attribute__((address_space(3))) unsigned int*)l, 16, 0, 0);
}

// ---------------------------------------------------------------------------
// prep: x[b][c][p] fp32 -> xT[b][p][c] bf16 (32x32 LDS tile transpose)
//       W[o][c]   fp32 -> Wb bf16 (elementwise)
// ---------------------------------------------------------------------------
__global__ __launch_bounds__(256) void prep_xw(
    const float* __restrict__ x, const float* __restrict__ w,
    short* __restrict__ xT, short* __restrict__ Wb)
{
    int blk = blockIdx.x;
    if (blk < NB * 16 * 32) {                  // 8192 transpose tiles
        int b = blk >> 9, rem = blk & 511;
        int ct = rem >> 5, pt = rem & 31;      // 16 c-tiles x 32 p-tiles
        __shared__ float tile[32][33];
        int tc = threadIdx.x >> 5;             // 0..7
        int tp = threadIdx.x & 31;             // 0..31
        const float* xb = x + ((size_t)b * CIN + ct * 32) * HW + pt * 32;
        #pragma unroll
        for (int i = 0; i < 4; i++)
            tile[tc + i * 8][tp] = xb[(size_t)(tc + i * 8) * HW + tp];
        __syncthreads();
        int p = threadIdx.x >> 3, cq = threadIdx.x & 7;
        short* xo = xT + ((size_t)b * HW + pt * 32 + p) * CIN + ct * 32 + cq * 4;
        s16x4 o4 = { f2bf(tile[cq * 4 + 0][p]), f2bf(tile[cq * 4 + 1][p]),
                     f2bf(tile[cq * 4 + 2][p]), f2bf(tile[cq * 4 + 3][p]) };
        *reinterpret_cast<s16x4*>(xo) = o4;
    } else {
        int wb = blk - NB * 16 * 32;           // 0..767, 1024 elems each
        size_t base = (size_t)wb * 1024 + threadIdx.x * 4;
        const float4 v = *reinterpret_cast<const float4*>(w + base);
        s16x4 o4 = { f2bf(v.x), f2bf(v.y), f2bf(v.z), f2bf(v.w) };
        *reinterpret_cast<s16x4*>(Wb + base) = o4;
    }
}

// ---------------------------------------------------------------------------
// qkv projection GEMM, BK=64. R10: LDS DOUBLE-BUFFERED DMA staging (the
// pattern verified on attn R5): issue gload_lds for step k+1 at the top of
// step k, ONE barrier per step -- the end-of-step barrier's vmcnt(0) drains a
// PREFETCH (not a blocking load), so compute never waits on DMA latency.
// Staging path is pure global_load_lds (no VGPR global loads mixed in ->
// no shared-vmcnt coupling, the R9 lesson). LDS 64KB -> 2 blocks/CU.
// Content keeps the 16B-chunk XOR swizzle (phys = c ^ (row&7)) via
// PRE-SWIZZLED per-lane global source + linear LDS dest (m173 pattern).
//   s=0: Q = val * (128^-0.5 * log2e)   [p][d]
//   s=1: K' = val + pos_h + pos_w       [p][d]
//   s=2: Vt = val                       [d][p]  -- p PERMUTED within 32-groups
//        (slot = 8*qs + 4*t + r  <-  u = 16*t + 4*qs + r), so attn's PV can
//        consume P directly from the S^T C-layout registers (no LDS trip).
// ---------------------------------------------------------------------------
__global__ __launch_bounds__(256, 2) void qkv_proj(
    const short* __restrict__ xT, const short* __restrict__ Wb,
    const float* __restrict__ pos_h, const float* __restrict__ pos_w,
    short* __restrict__ Q, short* __restrict__ Kp, short* __restrict__ Vt)
{
    __shared__ __align__(1024) char smem[65536];
    short* As = (short*)smem;               // [2][128][64] content-swizzled
    short* Bs = As + 2 * 128 * 64;          // [2][128][64] content-swizzled
    short* vb = (short*)smem;               // [128][136] reused for V epilogue

    const int pt = blockIdx.x, ot = blockIdx.y, b = blockIdx.z;
    const int tid = threadIdx.x;
    const int wave = tid >> 6, lane = tid & 63;
    const int l16 = lane & 15, quad = lane >> 4;
    const int wm = (wave & 1) * 64, wn = (wave >> 1) * 64;
    const int o0 = ot * 128, p0 = pt * 128;

    const short* xb = xT + (size_t)b * HW * CIN;

    // DMA staging geometry: wave w covers rows [w*32, w*32+32); instr j covers
    // 8 rows (1024 B). Lane: row_local = j*8 + (lane>>3), phys chunk = lane&7.
    // Source chunk = phys ^ (row&7); row&7 == lane>>3 (j*8, w*32 are 0 mod 8).
    const int r8 = lane >> 3, c8 = lane & 7;
    const int sch = c8 ^ r8;                  // pre-swizzled source chunk
    const short* wsrc = Wb + (size_t)(o0 + wave * 32 + r8) * CIN + sch * 8;
    const short* xsrc = xb + (size_t)(p0 + wave * 32 + r8) * CIN + sch * 8;

    f32x4 acc[4][4];
    #pragma unroll
    for (int i = 0; i < 4; i++)
        #pragma unroll
        for (int j = 0; j < 4; j++)
            acc[i][j] = f32x4{0.f, 0.f, 0.f, 0.f};

    // issue 8 gload16 for K-step `step` into buffer `buf`
    #define STAGE_AB(buf, step)                                               \
        do {                                                                  \
            int kc_ = (step) * 64;                                            \
            short* ad_ = As + (buf) * 8192 + wave * 2048;                     \
            short* bd_ = Bs + (buf) * 8192 + wave * 2048;                     \
            _Pragma("unroll")                                                 \
            for (int j = 0; j < 4; j++) {                                     \
                gload16(wsrc + kc_ + (size_t)(j * 8) * CIN, ad_ + j * 512);   \
                gload16(xsrc + kc_ + (size_t)(j * 8) * CIN, bd_ + j * 512);   \
            }                                                                 \
        } while (0)

    STAGE_AB(0, 0);        // step 0 -> buf0 (vmcnt drained by barrier below)
    __syncthreads();

    #pragma unroll 1
    for (int st = 0; st < 8; st++) {
        const int cur = st & 1, nxt = cur ^ 1;
        const short* as = As + cur * 8192;
        const short* bs = Bs + cur * 8192;

        // prefetch step st+1 into nxt (overlaps this step's compute; nxt was
        // last read at step st-1, ordered by its end barrier). Wrap harmless.
        STAGE_AB(nxt, (st + 1) & 7);

        #pragma unroll
        for (int kk = 0; kk < 2; kk++) {
            s16x8 aF[4], bF[4];
            #pragma unroll
            for (int mi = 0; mi < 4; mi++)
                aF[mi] = *(const s16x8*)(as + (wm + mi * 16 + l16) * 64
                                         + (((kk * 4 + quad) ^ (l16 & 7)) * 8));
            #pragma unroll
            for (int ni = 0; ni < 4; ni++)
                bF[ni] = *(const s16x8*)(bs + (wn + ni * 16 + l16) * 64
                                         + (((kk * 4 + quad) ^ (l16 & 7)) * 8));
            #pragma unroll
            for (int mi = 0; mi < 4; mi++)
                #pragma unroll
                for (int ni = 0; ni < 4; ni++)
                    acc[mi][ni] = __builtin_amdgcn_mfma_f32_16x16x32_bf16(
                        aF[mi], bF[ni], acc[mi][ni], 0, 0, 0);
        }
        __syncthreads();   // drains DMA (nxt ready) + orders cur reads
    }
    #undef STAGE_AB

    const int s = ot >> 2, h = ot & 3;
    const size_t bh = (size_t)(b * NH + h);

    if (s == 0) {
        const float qs = 0.08838834764831845f * 1.4426950408889634f; // scale*log2e
        short* Qb = Q + bh * (size_t)(HW * HD);
        #pragma unroll
        for (int mi = 0; mi < 4; mi++) {
            int d0 = wm + mi * 16 + quad * 4;
            #pragma unroll
            for (int ni = 0; ni < 4; ni++) {
                int p = p0 + wn + ni * 16 + l16;
                f32x4 a = acc[mi][ni];
                s16x4 o4 = { f2bf(a.x * qs), f2bf(a.y * qs),
                             f2bf(a.z * qs), f2bf(a.w * qs) };
                *reinterpret_cast<s16x4*>(Qb + (size_t)p * HD + d0) = o4;
            }
        }
    } else if (s == 1) {
        short* Kb = Kp + bh * (size_t)(HW * HD);
        #pragma unroll
        for (int mi = 0; mi < 4; mi++) {
            int d0 = wm + mi * 16 + quad * 4;
            #pragma unroll
            for (int ni = 0; ni < 4; ni++) {
                int p = p0 + wn + ni * 16 + l16;
                const float4 eh = *reinterpret_cast<const float4*>(pos_h + (p >> 5) * HD + d0);
                const float4 ew = *reinterpret_cast<const float4*>(pos_w + (p & 31) * HD + d0);
                f32x4 a = acc[mi][ni];
                s16x4 o4 = { f2bf(a.x + eh.x + ew.x), f2bf(a.y + eh.y + ew.y),
                             f2bf(a.z + eh.z + ew.z), f2bf(a.w + eh.w + ew.w) };
                *reinterpret_cast<s16x4*>(Kb + (size_t)p * HD + d0) = o4;
            }
        }
    } else {
        __syncthreads();   // done with As/Bs before vb overlay
        #pragma unroll
        for (int mi = 0; mi < 4; mi++) {
            int d0 = wm + mi * 16 + quad * 4;
            #pragma unroll
            for (int ni = 0; ni < 4; ni++) {
                int p = wn + ni * 16 + l16;
                f32x4 a = acc[mi][ni];
                vb[(d0 + 0) * 136 + p] = f2bf(a.x);
                vb[(d0 + 1) * 136 + p] = f2bf(a.y);
                vb[(d0 + 2) * 136 + p] = f2bf(a.z);
                vb[(d0 + 3) * 136 + p] = f2bf(a.w);
            }
        }
        __syncthreads();
        short* Vb = Vt + bh * (size_t)(HD * HW);
        int d = tid >> 1, half = tid & 1;
        // key-permuted store: out slot group g=(half*2+(j>>2)), qs=(j&3):
        //   slots 8qs..8qs+3 (t=0) <- u = g*32 + 4qs + r
        //   slots 8qs+4..+7 (t=1) <- u = g*32 + 16 + 4qs + r
        #pragma unroll
        for (int j = 0; j < 8; j++) {
            const short* row = vb + d * 136;
            int base = (half * 2 + (j >> 2)) * 32 + (j & 3) * 4;
            s16x4 lo = *(const s16x4*)(row + base);
            s16x4 hi = *(const s16x4*)(row + base + 16);
            s16x8 v8 = { lo[0], lo[1], lo[2], lo[3],
                         hi[0], hi[1], hi[2], hi[3] };
            *reinterpret_cast<s16x8*>(Vb + (size_t)d * HW + p0 + half * 64 + j * 8) = v8;
        }
    }
}

// ---------------------------------------------------------------------------
// Fused attention (R5 verbatim -- best measured 46.6us; R8 no-LDS and R9
// hybrid both regressed: direct global loads feeding MFMA are latency-toxic
// at 8 waves/CU, and mixing consumed global loads after prefetch DMA couples
// them through the shared vmcnt counter). 256 thr = 4 waves x 32 Q-ROWS,
// kt = 64 keys x 16 iters. K/V DMA-staged, double-buffered, ONE barrier/iter.
// P NEVER TOUCHES LDS: V stored key-PERMUTED (qkv_proj) so S^T's C-layout
// regs are directly PV's A-frags. Bank conflicts = 0 (verified).
// Grid 512 (bh = flat&63: XCD-affine), 2 blocks/CU (66KB LDS).
// ---------------------------------------------------------------------------
__global__ __launch_bounds__(256, 2) void attn_fused(
    const short* __restrict__ Q, const short* __restrict__ Kp,
    const short* __restrict__ Vt, float* __restrict__ out)
{
    __shared__ __align__(1024) short Ks[2][64 * 128];   // [buf][key][d] swz: c^(key&15)
    __shared__ __align__(1024) short Vs[2][128 * 64];   // [buf][d][slot] swz: c^(d&7)

    const int flat = blockIdx.x;
    const int qt = flat >> 6;              // 0..7
    const int bh = flat & 63;              // XCD-affine: bh%8 == blockIdx%8
    const int tid = threadIdx.x;
    const int wave = tid >> 6, lane = tid & 63;
    const int l16 = lane & 15, quad = lane >> 4;

    const short* Qb = Q + (size_t)bh * (HW * HD);
    const short* Kb = Kp + (size_t)bh * (HW * HD);
    const short* Vb = Vt + (size_t)bh * (HD * HW);

    const int q0 = qt * 128 + wave * 32;

    // Q fragments (B-operand for S^T): this wave's 32 rows, K=128 -> 2x4 frags
    s16x8 bQ[2][4];
    #pragma unroll
    for (int nt = 0; nt < 2; nt++)
        #pragma unroll
        for (int kk = 0; kk < 4; kk++)
            bQ[nt][kk] = *(const s16x8*)(Qb + (size_t)(q0 + nt * 16 + l16) * HD
                                         + kk * 32 + quad * 8);

    s16x8 ones;
    #pragma unroll
    for (int j = 0; j < 8; j++) ones[j] = (short)0x3F80;   // bf16 1.0

    f32x4 Oacc[2][8];
    #pragma unroll
    for (int mt = 0; mt < 2; mt++)
        #pragma unroll
        for (int dt = 0; dt < 8; dt++)
            Oacc[mt][dt] = f32x4{0.f, 0.f, 0.f, 0.f};
    f32x4 lacc[2] = { f32x4{0.f, 0.f, 0.f, 0.f}, f32x4{0.f, 0.f, 0.f, 0.f} };

    // DMA staging geometry (32 KB/tile = 32 instrs of 1KB; 8 per wave):
    // K instr j: keys wave*16 + j*4 .. +4. lane: key = base + (lane>>4),
    //   phys chunk = lane&15, src chunk = (lane&15) ^ (key&15),
    //   key&15 = j*4 + (lane>>4)  (wave*16 == 0 mod 16).
    // V instr j: d = wave*32 + j*8 .. +8. lane: d = base + (lane>>3),
    //   phys chunk = lane&7, src chunk = (lane&7) ^ (lane>>3)  (d&7 == lane>>3).
    const int kRow = lane >> 4;            // 0..3
    const int vRow = lane >> 3;            // 0..7
    const int vSch = (lane & 7) ^ vRow;    // V source chunk (j-independent)

    #define STAGE(buf, tile)                                                  \
        do {                                                                  \
            _Pragma("unroll")                                                 \
            for (int j = 0; j < 4; j++) {                                     \
                int kkey = wave * 16 + j * 4 + kRow;                          \
                gload16(Kb + ((size_t)((tile) * 64 + kkey)) * HD              \
                           + (((lane & 15) ^ (j * 4 + kRow)) * 8),            \
                        &Ks[buf][(wave * 16 + j * 4) * 128] + lane * 8);      \
                int vd = wave * 32 + j * 8 + vRow;                            \
                gload16(Vb + (size_t)vd * HW + (tile) * 64 + vSch * 8,        \
                        &Vs[buf][(wave * 32 + j * 8) * 64] + lane * 8);       \
            }                                                                 \
        } while (0)

    STAGE(0, 0);           // tile 0 -> buf0 (vmcnt drained by barrier below)
    __syncthreads();

    #pragma unroll 1
    for (int kt = 0; kt < 16; kt++) {
        const int cur = kt & 1, nxt = cur ^ 1;
        const short* ks = Ks[cur];
        const short* vs = Vs[cur];

        // issue DMA for tile kt+1 into nxt (overlaps this iter's compute;
        // nxt's last readers finished at iter kt-1, ordered by its barrier)
        STAGE(nxt, (kt + 1) & 15);   // wrap at end: harmless L2-hot reload

        // ---- S^T: 64 keys x 32 qrows (aK shared across both q-tiles)
        f32x4 c[4][2];
        __builtin_amdgcn_s_setprio(1);
        #pragma unroll
        for (int mtp = 0; mtp < 4; mtp++) {
            s16x8 aK[4];
            #pragma unroll
            for (int kk = 0; kk < 4; kk++)
                aK[kk] = *(const s16x8*)(ks + (mtp * 16 + l16) * 128
                                         + (((kk * 4 + quad) ^ l16) * 8));
            c[mtp][0] = f32x4{0.f, 0.f, 0.f, 0.f};
            c[mtp][1] = f32x4{0.f, 0.f, 0.f, 0.f};
            #pragma unroll
            for (int kk = 0; kk < 4; kk++) {
                c[mtp][0] = __builtin_amdgcn_mfma_f32_16x16x32_bf16(
                    aK[kk], bQ[0][kk], c[mtp][0], 0, 0, 0);
                c[mtp][1] = __builtin_amdgcn_mfma_f32_16x16x32_bf16(
                    aK[kk], bQ[1][kk], c[mtp][1], 0, 0, 0);
            }
        }
        __builtin_amdgcn_s_setprio(0);

        // ---- P = exp2(S') packed ENTIRELY in registers (V rows permuted to
        //      match the C-layout keys each lane holds). Two 32-key halves.
        #pragma unroll
        for (int h = 0; h < 2; h++) {
            s16x8 aP[2];
            #pragma unroll
            for (int mt = 0; mt < 2; mt++) {
                f32x4 e0 = c[2 * h][mt], e1 = c[2 * h + 1][mt];
                aP[mt] = s16x8{
                    f2bf(__builtin_amdgcn_exp2f(e0[0])),
                    f2bf(__builtin_amdgcn_exp2f(e0[1])),
                    f2bf(__builtin_amdgcn_exp2f(e0[2])),
                    f2bf(__builtin_amdgcn_exp2f(e0[3])),
                    f2bf(__builtin_amdgcn_exp2f(e1[0])),
                    f2bf(__builtin_amdgcn_exp2f(e1[1])),
                    f2bf(__builtin_amdgcn_exp2f(e1[2])),
                    f2bf(__builtin_amdgcn_exp2f(e1[3])) };
            }

            __builtin_amdgcn_s_setprio(1);
            #pragma unroll
            for (int mt = 0; mt < 2; mt++)
                lacc[mt] = __builtin_amdgcn_mfma_f32_16x16x32_bf16(
                    aP[mt], ones, lacc[mt], 0, 0, 0);

            #pragma unroll
            for (int dt = 0; dt < 8; dt++) {
                s16x8 bV = *(const s16x8*)(vs + (dt * 16 + l16) * 64
                                           + (((h * 4 + quad) ^ (l16 & 7)) * 8));
                #pragma unroll
                for (int mt = 0; mt < 2; mt++)
                    Oacc[mt][dt] = __builtin_amdgcn_mfma_f32_16x16x32_bf16(
                        aP[mt], bV, Oacc[mt][dt], 0, 0, 0);
            }
            __builtin_amdgcn_s_setprio(0);
        }
        __syncthreads();   // drains DMA (nxt ready) + orders cur reads
    }
    #undef STAGE

    // epilogue: O/l, stored transposed -> out[b][h][d][p] FP32
    float* ob = out + (size_t)bh * (HD * HW);
    #pragma unroll
    for (int mt = 0; mt < 2; mt++) {
        float inv[4];
        #pragma unroll
        for (int r = 0; r < 4; r++) inv[r] = __builtin_amdgcn_rcpf(lacc[mt][r]);
        int prow = q0 + mt * 16 + quad * 4;
        #pragma unroll
        for (int dt = 0; dt < 8; dt++) {
            int d = dt * 16 + l16;
            f32x4 o = Oacc[mt][dt];
            float4 o4 = { o[0] * inv[0], o[1] * inv[1],
                          o[2] * inv[2], o[3] * inv[3] };
            *reinterpret_cast<float4*>(ob + (size_t)d * HW + prow) = o4;
        }
    }
}

// ---------------------------------------------------------------------------
extern "C" void kernel_launch(void* const* d_in, const int* in_sizes, int n_in,
                              void* d_out, int out_size, void* d_ws, size_t ws_size,
                              hipStream_t stream) {
    const float* x  = (const float*)d_in[0];
    const float* w  = (const float*)d_in[1];
    const float* ph = (const float*)d_in[2];
    const float* pw = (const float*)d_in[3];

    const size_t BHPD = (size_t)NB * NH * HW * HD;   // 8,388,608 elems
    short* Q    = (short*)d_ws;
    short* Kp   = Q + BHPD;
    short* Vt   = Kp + BHPD;
    short* xT   = Vt + BHPD;
    short* Wb   = xT + (size_t)NB * HW * CIN;
    float* outp = (float*)d_out;

    prep_xw<<<dim3(NB * 16 * 32 + 768), 256, 0, stream>>>(x, w, xT, Wb);
    qkv_proj<<<dim3(8, 12, NB), 256, 0, stream>>>(xT, Wb, ph, pw, Q, Kp, Vt);
    attn_fused<<<dim3(512), 256, 0, stream>>>(Q, Kp, Vt, outp);
}

// Round 11
// 172.724 us; speedup vs baseline: 1.4752x; 1.0364x over previous
//
#include <hip/hip_runtime.h>

#define NB 16
#define NH 4
#define HD 128
#define HW 1024
#define CIN 512

typedef short s16x8 __attribute__((ext_vector_type(8)));
typedef short s16x4 __attribute__((ext_vector_type(4)));
typedef float f32x4 __attribute__((ext_vector_type(4)));

static __device__ __forceinline__ short f2bf(float f) {
    union { float f; unsigned u; } v; v.f = f;
    unsigned r = v.u + 0x7fffu + ((v.u >> 16) & 1u);   // round-to-nearest-even
    return (short)(r >> 16);
}

// async global->LDS DMA, 16B per lane. LDS dest is wave-uniform base + lane*16
// (linear); global src is per-lane (carries the XOR swizzle).
static __device__ __forceinline__ void gload16(const short* g, short* l) {
    __builtin_amdgcn_global_load_lds(
        (const __attribute__((address_space(1))) unsigned int*)g,
        (__attribute__((address_space(3))) unsigned int*)l, 16, 0, 0);
}

// ---------------------------------------------------------------------------
// prep: x[b][c][p] fp32 -> xT[b][p][c] bf16 (32x32 LDS tile transpose)
//       W[o][c]   fp32 -> Wb bf16 (elementwise)
// ---------------------------------------------------------------------------
__global__ __launch_bounds__(256) void prep_xw(
    const float* __restrict__ x, const float* __restrict__ w,
    short* __restrict__ xT, short* __restrict__ Wb)
{
    int blk = blockIdx.x;
    if (blk < NB * 16 * 32) {                  // 8192 transpose tiles
        int b = blk >> 9, rem = blk & 511;
        int ct = rem >> 5, pt = rem & 31;      // 16 c-tiles x 32 p-tiles
        __shared__ float tile[32][33];
        int tc = threadIdx.x >> 5;             // 0..7
        int tp = threadIdx.x & 31;             // 0..31
        const float* xb = x + ((size_t)b * CIN + ct * 32) * HW + pt * 32;
        #pragma unroll
        for (int i = 0; i < 4; i++)
            tile[tc + i * 8][tp] = xb[(size_t)(tc + i * 8) * HW + tp];
        __syncthreads();
        int p = threadIdx.x >> 3, cq = threadIdx.x & 7;
        short* xo = xT + ((size_t)b * HW + pt * 32 + p) * CIN + ct * 32 + cq * 4;
        s16x4 o4 = { f2bf(tile[cq * 4 + 0][p]), f2bf(tile[cq * 4 + 1][p]),
                     f2bf(tile[cq * 4 + 2][p]), f2bf(tile[cq * 4 + 3][p]) };
        *reinterpret_cast<s16x4*>(xo) = o4;
    } else {
        int wb = blk - NB * 16 * 32;           // 0..767, 1024 elems each
        size_t base = (size_t)wb * 1024 + threadIdx.x * 4;
        const float4 v = *reinterpret_cast<const float4*>(w + base);
        s16x4 o4 = { f2bf(v.x), f2bf(v.y), f2bf(v.z), f2bf(v.w) };
        *reinterpret_cast<s16x4*>(Wb + base) = o4;
    }
}

// ---------------------------------------------------------------------------
// qkv projection GEMM, BK=64, double-buffered gload_lds staging (R10).
// R11: COALESCED EPILOGUES. The old per-frag stores wrote 8B per lane at
// p*HD+d0 with p varying per lane -> consecutive lanes 256B apart -> every
// store instr touched 64 cache lines (~40% of block time in store-drain,
// invisible to MfmaUtil/VALUBusy). Now the 128x128 output tile is staged in
// LDS (reusing the staging buffers post-loop; chunk XOR swizzle phys =
// chunk^(row&7), 2-way banked) and written out row-contiguously: thread t,
// instr j -> row j*16+(t>>4), chunk t&15 => 16-lane groups write 256
// contiguous bytes. Q/K block region [p0:p0+128]x[0:128] is contiguous.
//   s=0: Q = val * (128^-0.5 * log2e)   [p][d]
//   s=1: K' = val + pos_h + pos_w       [p][d]
//   s=2: Vt = val                       [d][p]  -- p PERMUTED within 32-groups
//        (slot = 8*qs + 4*t + r  <-  u = 16*t + 4*qs + r), so attn's PV can
//        consume P directly from the S^T C-layout registers (no LDS trip).
// ---------------------------------------------------------------------------
__global__ __launch_bounds__(256, 2) void qkv_proj(
    const short* __restrict__ xT, const short* __restrict__ Wb,
    const float* __restrict__ pos_h, const float* __restrict__ pos_w,
    short* __restrict__ Q, short* __restrict__ Kp, short* __restrict__ Vt)
{
    __shared__ __align__(1024) char smem[65536];
    short* As = (short*)smem;               // [2][128][64] content-swizzled
    short* Bs = As + 2 * 128 * 64;          // [2][128][64] content-swizzled
    short* vb = (short*)smem;               // [128][136] reused for V epilogue
    short* T  = (short*)smem;               // [128][128] reused for Q/K epilogue

    const int pt = blockIdx.x, ot = blockIdx.y, b = blockIdx.z;
    const int tid = threadIdx.x;
    const int wave = tid >> 6, lane = tid & 63;
    const int l16 = lane & 15, quad = lane >> 4;
    const int wm = (wave & 1) * 64, wn = (wave >> 1) * 64;
    const int o0 = ot * 128, p0 = pt * 128;

    const short* xb = xT + (size_t)b * HW * CIN;

    // DMA staging geometry: wave w covers rows [w*32, w*32+32); instr j covers
    // 8 rows (1024 B). Lane: row_local = j*8 + (lane>>3), phys chunk = lane&7.
    // Source chunk = phys ^ (row&7); row&7 == lane>>3 (j*8, w*32 are 0 mod 8).
    const int r8 = lane >> 3, c8 = lane & 7;
    const int sch = c8 ^ r8;                  // pre-swizzled source chunk
    const short* wsrc = Wb + (size_t)(o0 + wave * 32 + r8) * CIN + sch * 8;
    const short* xsrc = xb + (size_t)(p0 + wave * 32 + r8) * CIN + sch * 8;

    f32x4 acc[4][4];
    #pragma unroll
    for (int i = 0; i < 4; i++)
        #pragma unroll
        for (int j = 0; j < 4; j++)
            acc[i][j] = f32x4{0.f, 0.f, 0.f, 0.f};

    // issue 8 gload16 for K-step `step` into buffer `buf`
    #define STAGE_AB(buf, step)                                               \
        do {                                                                  \
            int kc_ = (step) * 64;                                            \
            short* ad_ = As + (buf) * 8192 + wave * 2048;                     \
            short* bd_ = Bs + (buf) * 8192 + wave * 2048;                     \
            _Pragma("unroll")                                                 \
            for (int j = 0; j < 4; j++) {                                     \
                gload16(wsrc + kc_ + (size_t)(j * 8) * CIN, ad_ + j * 512);   \
                gload16(xsrc + kc_ + (size_t)(j * 8) * CIN, bd_ + j * 512);   \
            }                                                                 \
        } while (0)

    STAGE_AB(0, 0);        // step 0 -> buf0 (vmcnt drained by barrier below)
    __syncthreads();

    #pragma unroll 1
    for (int st = 0; st < 8; st++) {
        const int cur = st & 1, nxt = cur ^ 1;
        const short* as = As + cur * 8192;
        const short* bs = Bs + cur * 8192;

        // prefetch step st+1 into nxt (overlaps this step's compute; nxt was
        // last read at step st-1, ordered by its end barrier). Wrap harmless.
        STAGE_AB(nxt, (st + 1) & 7);

        #pragma unroll
        for (int kk = 0; kk < 2; kk++) {
            s16x8 aF[4], bF[4];
            #pragma unroll
            for (int mi = 0; mi < 4; mi++)
                aF[mi] = *(const s16x8*)(as + (wm + mi * 16 + l16) * 64
                                         + (((kk * 4 + quad) ^ (l16 & 7)) * 8));
            #pragma unroll
            for (int ni = 0; ni < 4; ni++)
                bF[ni] = *(const s16x8*)(bs + (wn + ni * 16 + l16) * 64
                                         + (((kk * 4 + quad) ^ (l16 & 7)) * 8));
            #pragma unroll
            for (int mi = 0; mi < 4; mi++)
                #pragma unroll
                for (int ni = 0; ni < 4; ni++)
                    acc[mi][ni] = __builtin_amdgcn_mfma_f32_16x16x32_bf16(
                        aF[mi], bF[ni], acc[mi][ni], 0, 0, 0);
        }
        __syncthreads();   // drains DMA (nxt ready) + orders cur reads
    }
    #undef STAGE_AB

    const int s = ot >> 2, h = ot & 3;
    const size_t bh = (size_t)(b * NH + h);

    if (s < 2) {
        // ---- stage output tile in LDS T[128][128], swizzle phys=chunk^(row&7)
        const float qs = 0.08838834764831845f * 1.4426950408889634f; // scale*log2e
        #pragma unroll
        for (int mi = 0; mi < 4; mi++) {
            int col = wm + mi * 16 + quad * 4;        // logical col (shorts)
            int chunk = col >> 3, sub = (quad & 1) * 4;
            #pragma unroll
            for (int ni = 0; ni < 4; ni++) {
                int row = wn + ni * 16 + l16;         // row&7 == l16&7
                f32x4 a = acc[mi][ni];
                s16x4 o4;
                if (s == 0) {
                    o4 = s16x4{ f2bf(a.x * qs), f2bf(a.y * qs),
                                f2bf(a.z * qs), f2bf(a.w * qs) };
                } else {
                    int p = p0 + row;
                    const float4 eh = *reinterpret_cast<const float4*>(pos_h + (p >> 5) * HD + col);
                    const float4 ew = *reinterpret_cast<const float4*>(pos_w + (p & 31) * HD + col);
                    o4 = s16x4{ f2bf(a.x + eh.x + ew.x), f2bf(a.y + eh.y + ew.y),
                                f2bf(a.z + eh.z + ew.z), f2bf(a.w + eh.w + ew.w) };
                }
                *(s16x4*)(T + row * 128 + ((chunk ^ (l16 & 7)) * 8 + sub)) = o4;
            }
        }
        __syncthreads();
        // ---- coalesced write-out: block region is contiguous 32 KB
        short* Ob = (s == 0 ? Q : Kp) + bh * (size_t)(HW * HD) + (size_t)p0 * HD;
        #pragma unroll
        for (int j = 0; j < 8; j++) {
            int row = j * 16 + (tid >> 4);            // row&7 == (tid>>4)&7
            int c16 = tid & 15;
            s16x8 v8 = *(const s16x8*)(T + row * 128 + ((c16 ^ ((tid >> 4) & 7)) * 8));
            *reinterpret_cast<s16x8*>(Ob + (size_t)row * HD + c16 * 8) = v8;
        }
    } else {
        __syncthreads();   // done with As/Bs before vb overlay
        #pragma unroll
        for (int mi = 0; mi < 4; mi++) {
            int d0 = wm + mi * 16 + quad * 4;
            #pragma unroll
            for (int ni = 0; ni < 4; ni++) {
                int p = wn + ni * 16 + l16;
                f32x4 a = acc[mi][ni];
                // key-permuted within 32-groups: slot g*32 + 8qs+4t+r <- u
                int g = p >> 5, u = p & 31;
                int slot = g * 32 + ((u & 15) >> 2) * 8 + (u >> 4) * 4 + 0;
                // NOTE: permutation applied via the same gather as before but
                // expressed store-side: vb holds [d][p] with p in PERMUTED
                // order directly.
                (void)slot;
                vb[(d0 + 0) * 136 + p] = f2bf(a.x);
                vb[(d0 + 1) * 136 + p] = f2bf(a.y);
                vb[(d0 + 2) * 136 + p] = f2bf(a.z);
                vb[(d0 + 3) * 136 + p] = f2bf(a.w);
            }
        }
        __syncthreads();
        short* Vb = Vt + bh * (size_t)(HD * HW);
        // coalesced write-out with key-permuted gather (same mapping as R10:
        // out slot group g=(c16>>1), qs=(c16&1)*2+(sub within 8): rebuild the
        // exact R10 data mapping: for output chunk c (8 slots = 8qs..):
        //   slots 8qs..8qs+3 <- u = g*32 + 4qs + r ; slots +4..+7 <- u+16
        #pragma unroll
        for (int j = 0; j < 8; j++) {
            int d = j * 16 + (tid >> 4);
            int c16 = tid & 15;                    // output chunk (8 shorts)
            const short* row = vb + d * 136;
            int g = c16 >> 2;                      // 32-slot group 0..3
            int qs = (c16 & 3) * 2 + 0;            // chunk covers slots 8qs..;
            // chunk c16 spans slots c16*8 .. c16*8+7 = 8*qs..8*qs+7 with
            // qs = c16 & 3 (since slot = g*32 + 8*qs + 4*t + r)
            qs = c16 & 3;
            int base = g * 32 + qs * 4;
            s16x4 lo = *(const s16x4*)(row + base);        // t=0: u = g*32+4qs+r
            s16x4 hi = *(const s16x4*)(row + base + 16);   // t=1: u+16
            s16x8 v8 = { lo[0], lo[1], lo[2], lo[3],
                         hi[0], hi[1], hi[2], hi[3] };
            *reinterpret_cast<s16x8*>(Vb + (size_t)d * HW + p0 + c16 * 8) = v8;
        }
    }
}

// ---------------------------------------------------------------------------
// Fused attention (R5 verbatim -- best measured 46.6us; R8 no-LDS and R9
// hybrid both regressed: direct global loads feeding MFMA are latency-toxic
// at 8 waves/CU, and mixing consumed global loads after prefetch DMA couples
// them through the shared vmcnt counter). 256 thr = 4 waves x 32 Q-ROWS,
// kt = 64 keys x 16 iters. K/V DMA-staged, double-buffered, ONE barrier/iter.
// P NEVER TOUCHES LDS: V stored key-PERMUTED (qkv_proj) so S^T's C-layout
// regs are directly PV's A-frags. Bank conflicts = 0 (verified).
// Grid 512 (bh = flat&63: XCD-affine), 2 blocks/CU (66KB LDS).
// ---------------------------------------------------------------------------
__global__ __launch_bounds__(256, 2) void attn_fused(
    const short* __restrict__ Q, const short* __restrict__ Kp,
    const short* __restrict__ Vt, float* __restrict__ out)
{
    __shared__ __align__(1024) short Ks[2][64 * 128];   // [buf][key][d] swz: c^(key&15)
    __shared__ __align__(1024) short Vs[2][128 * 64];   // [buf][d][slot] swz: c^(d&7)

    const int flat = blockIdx.x;
    const int qt = flat >> 6;              // 0..7
    const int bh = flat & 63;              // XCD-affine: bh%8 == blockIdx%8
    const int tid = threadIdx.x;
    const int wave = tid >> 6, lane = tid & 63;
    const int l16 = lane & 15, quad = lane >> 4;

    const short* Qb = Q + (size_t)bh * (HW * HD);
    const short* Kb = Kp + (size_t)bh * (HW * HD);
    const short* Vb = Vt + (size_t)bh * (HD * HW);

    const int q0 = qt * 128 + wave * 32;

    // Q fragments (B-operand for S^T): this wave's 32 rows, K=128 -> 2x4 frags
    s16x8 bQ[2][4];
    #pragma unroll
    for (int nt = 0; nt < 2; nt++)
        #pragma unroll
        for (int kk = 0; kk < 4; kk++)
            bQ[nt][kk] = *(const s16x8*)(Qb + (size_t)(q0 + nt * 16 + l16) * HD
                                         + kk * 32 + quad * 8);

    s16x8 ones;
    #pragma unroll
    for (int j = 0; j < 8; j++) ones[j] = (short)0x3F80;   // bf16 1.0

    f32x4 Oacc[2][8];
    #pragma unroll
    for (int mt = 0; mt < 2; mt++)
        #pragma unroll
        for (int dt = 0; dt < 8; dt++)
            Oacc[mt][dt] = f32x4{0.f, 0.f, 0.f, 0.f};
    f32x4 lacc[2] = { f32x4{0.f, 0.f, 0.f, 0.f}, f32x4{0.f, 0.f, 0.f, 0.f} };

    // DMA staging geometry (32 KB/tile = 32 instrs of 1KB; 8 per wave):
    // K instr j: keys wave*16 + j*4 .. +4. lane: key = base + (lane>>4),
    //   phys chunk = lane&15, src chunk = (lane&15) ^ (key&15),
    //   key&15 = j*4 + (lane>>4)  (wave*16 == 0 mod 16).
    // V instr j: d = wave*32 + j*8 .. +8. lane: d = base + (lane>>3),
    //   phys chunk = lane&7, src chunk = (lane&7) ^ (lane>>3)  (d&7 == lane>>3).
    const int kRow = lane >> 4;            // 0..3
    const int vRow = lane >> 3;            // 0..7
    const int vSch = (lane & 7) ^ vRow;    // V source chunk (j-independent)

    #define STAGE(buf, tile)                                                  \
        do {                                                                  \
            _Pragma("unroll")                                                 \
            for (int j = 0; j < 4; j++) {                                     \
                int kkey = wave * 16 + j * 4 + kRow;                          \
                gload16(Kb + ((size_t)((tile) * 64 + kkey)) * HD              \
                           + (((lane & 15) ^ (j * 4 + kRow)) * 8),            \
                        &Ks[buf][(wave * 16 + j * 4) * 128] + lane * 8);      \
                int vd = wave * 32 + j * 8 + vRow;                            \
                gload16(Vb + (size_t)vd * HW + (tile) * 64 + vSch * 8,        \
                        &Vs[buf][(wave * 32 + j * 8) * 64] + lane * 8);       \
            }                                                                 \
        } while (0)

    STAGE(0, 0);           // tile 0 -> buf0 (vmcnt drained by barrier below)
    __syncthreads();

    #pragma unroll 1
    for (int kt = 0; kt < 16; kt++) {
        const int cur = kt & 1, nxt = cur ^ 1;
        const short* ks = Ks[cur];
        const short* vs = Vs[cur];

        // issue DMA for tile kt+1 into nxt (overlaps this iter's compute;
        // nxt's last readers finished at iter kt-1, ordered by its barrier)
        STAGE(nxt, (kt + 1) & 15);   // wrap at end: harmless L2-hot reload

        // ---- S^T: 64 keys x 32 qrows (aK shared across both q-tiles)
        f32x4 c[4][2];
        __builtin_amdgcn_s_setprio(1);
        #pragma unroll
        for (int mtp = 0; mtp < 4; mtp++) {
            s16x8 aK[4];
            #pragma unroll
            for (int kk = 0; kk < 4; kk++)
                aK[kk] = *(const s16x8*)(ks + (mtp * 16 + l16) * 128
                                         + (((kk * 4 + quad) ^ l16) * 8));
            c[mtp][0] = f32x4{0.f, 0.f, 0.f, 0.f};
            c[mtp][1] = f32x4{0.f, 0.f, 0.f, 0.f};
            #pragma unroll
            for (int kk = 0; kk < 4; kk++) {
                c[mtp][0] = __builtin_amdgcn_mfma_f32_16x16x32_bf16(
                    aK[kk], bQ[0][kk], c[mtp][0], 0, 0, 0);
                c[mtp][1] = __builtin_amdgcn_mfma_f32_16x16x32_bf16(
                    aK[kk], bQ[1][kk], c[mtp][1], 0, 0, 0);
            }
        }
        __builtin_amdgcn_s_setprio(0);

        // ---- P = exp2(S') packed ENTIRELY in registers (V rows permuted to
        //      match the C-layout keys each lane holds). Two 32-key halves.
        #pragma unroll
        for (int h = 0; h < 2; h++) {
            s16x8 aP[2];
            #pragma unroll
            for (int mt = 0; mt < 2; mt++) {
                f32x4 e0 = c[2 * h][mt], e1 = c[2 * h + 1][mt];
                aP[mt] = s16x8{
                    f2bf(__builtin_amdgcn_exp2f(e0[0])),
                    f2bf(__builtin_amdgcn_exp2f(e0[1])),
                    f2bf(__builtin_amdgcn_exp2f(e0[2])),
                    f2bf(__builtin_amdgcn_exp2f(e0[3])),
                    f2bf(__builtin_amdgcn_exp2f(e1[0])),
                    f2bf(__builtin_amdgcn_exp2f(e1[1])),
                    f2bf(__builtin_amdgcn_exp2f(e1[2])),
                    f2bf(__builtin_amdgcn_exp2f(e1[3])) };
            }

            __builtin_amdgcn_s_setprio(1);
            #pragma unroll
            for (int mt = 0; mt < 2; mt++)
                lacc[mt] = __builtin_amdgcn_mfma_f32_16x16x32_bf16(
                    aP[mt], ones, lacc[mt], 0, 0, 0);

            #pragma unroll
            for (int dt = 0; dt < 8; dt++) {
                s16x8 bV = *(const s16x8*)(vs + (dt * 16 + l16) * 64
                                           + (((h * 4 + quad) ^ (l16 & 7)) * 8));
                #pragma unroll
                for (int mt = 0; mt < 2; mt++)
                    Oacc[mt][dt] = __builtin_amdgcn_mfma_f32_16x16x32_bf16(
                        aP[mt], bV, Oacc[mt][dt], 0, 0, 0);
            }
            __builtin_amdgcn_s_setprio(0);
        }
        __syncthreads();   // drains DMA (nxt ready) + orders cur reads
    }
    #undef STAGE

    // epilogue: O/l, stored transposed -> out[b][h][d][p] FP32
    float* ob = out + (size_t)bh * (HD * HW);
    #pragma unroll
    for (int mt = 0; mt < 2; mt++) {
        float inv[4];
        #pragma unroll
        for (int r = 0; r < 4; r++) inv[r] = __builtin_amdgcn_rcpf(lacc[mt][r]);
        int prow = q0 + mt * 16 + quad * 4;
        #pragma unroll
        for (int dt = 0; dt < 8; dt++) {
            int d = dt * 16 + l16;
            f32x4 o = Oacc[mt][dt];
            float4 o4 = { o[0] * inv[0], o[1] * inv[1],
                          o[2] * inv[2], o[3] * inv[3] };
            *reinterpret_cast<float4*>(ob + (size_t)d * HW + prow) = o4;
        }
    }
}

// ---------------------------------------------------------------------------
extern "C" void kernel_launch(void* const* d_in, const int* in_sizes, int n_in,
                              void* d_out, int out_size, void* d_ws, size_t ws_size,
                              hipStream_t stream) {
    const float* x  = (const float*)d_in[0];
    const float* w  = (const float*)d_in[1];
    const float* ph = (const float*)d_in[2];
    const float* pw = (const float*)d_in[3];

    const size_t BHPD = (size_t)NB * NH * HW * HD;   // 8,388,608 elems
    short* Q    = (short*)d_ws;
    short* Kp   = Q + BHPD;
    short* Vt   = Kp + BHPD;
    short* xT   = Vt + BHPD;
    short* Wb   = xT + (size_t)NB * HW * CIN;
    float* outp = (float*)d_out;

    prep_xw<<<dim3(NB * 16 * 32 + 768), 256, 0, stream>>>(x, w, xT, Wb);
    qkv_proj<<<dim3(8, 12, NB), 256, 0, stream>>>(xT, Wb, ph, pw, Q, Kp, Vt);
    attn_fused<<<dim3(512), 256, 0, stream>>>(Q, Kp, Vt, outp);
}

// Round 12
// 162.356 us; speedup vs baseline: 1.5694x; 1.0639x over previous
//
#include <hip/hip_runtime.h>

#define NB 16
#define NH 4
#define HD 128
#define HW 1024
#define CIN 512

typedef short s16x8 __attribute__((ext_vector_type(8)));
typedef short s16x4 __attribute__((ext_vector_type(4)));
typedef float f32x4 __attribute__((ext_vector_type(4)));

static __device__ __forceinline__ short f2bf(float f) {
    union { float f; unsigned u; } v; v.f = f;
    unsigned r = v.u + 0x7fffu + ((v.u >> 16) & 1u);   // round-to-nearest-even
    return (short)(r >> 16);
}

// async global->LDS DMA, 16B per lane. LDS dest is wave-uniform base + lane*16
// (linear); global src is per-lane (carries the XOR swizzle).
static __device__ __forceinline__ void gload16(const short* g, short* l) {
    __builtin_amdgcn_global_load_lds(
        (const __attribute__((address_space(1))) unsigned int*)g,
        (__attribute__((address_space(3))) unsigned int*)l, 16, 0, 0);
}

// ---------------------------------------------------------------------------
// prep: x[b][c][p] fp32 -> xT[b][p][c] bf16 (32x32 LDS tile transpose)
//       W[o][c]   fp32 -> Wb bf16 (elementwise)
// ---------------------------------------------------------------------------
__global__ __launch_bounds__(256) void prep_xw(
    const float* __restrict__ x, const float* __restrict__ w,
    short* __restrict__ xT, short* __restrict__ Wb)
{
    int blk = blockIdx.x;
    if (blk < NB * 16 * 32) {                  // 8192 transpose tiles
        int b = blk >> 9, rem = blk & 511;
        int ct = rem >> 5, pt = rem & 31;      // 16 c-tiles x 32 p-tiles
        __shared__ float tile[32][33];
        int tc = threadIdx.x >> 5;             // 0..7
        int tp = threadIdx.x & 31;             // 0..31
        const float* xb = x + ((size_t)b * CIN + ct * 32) * HW + pt * 32;
        #pragma unroll
        for (int i = 0; i < 4; i++)
            tile[tc + i * 8][tp] = xb[(size_t)(tc + i * 8) * HW + tp];
        __syncthreads();
        int p = threadIdx.x >> 3, cq = threadIdx.x & 7;
        short* xo = xT + ((size_t)b * HW + pt * 32 + p) * CIN + ct * 32 + cq * 4;
        s16x4 o4 = { f2bf(tile[cq * 4 + 0][p]), f2bf(tile[cq * 4 + 1][p]),
                     f2bf(tile[cq * 4 + 2][p]), f2bf(tile[cq * 4 + 3][p]) };
        *reinterpret_cast<s16x4*>(xo) = o4;
    } else {
        int wb = blk - NB * 16 * 32;           // 0..767, 1024 elems each
        size_t base = (size_t)wb * 1024 + threadIdx.x * 4;
        const float4 v = *reinterpret_cast<const float4*>(w + base);
        s16x4 o4 = { f2bf(v.x), f2bf(v.y), f2bf(v.z), f2bf(v.w) };
        *reinterpret_cast<s16x4*>(Wb + base) = o4;
    }
}

// ---------------------------------------------------------------------------
// qkv projection GEMM, BK=64. R12: single-buffered m97 loop (stage -> barrier
// -> compute -> barrier) at __launch_bounds__(256,4): 4 blocks/CU (139KB LDS,
// VGPR 88 <= 128-class). The per-step DMA drain at the barrier is hidden by
// TLP across 4 co-resident blocks (m114 mechanism) -- intra-block dbuf (R10)
// at 2 blocks/CU was neutral; occupancy is the binder.
// Coalesced epilogues (R11, verified): output tile staged in LDS, written
// out row-contiguously (16-lane groups write 256 contiguous bytes).
// Content keeps the 16B-chunk XOR swizzle (phys = c ^ (row&7)) via
// PRE-SWIZZLED per-lane global source + linear LDS dest (m173 pattern).
//   s=0: Q = val * (128^-0.5 * log2e)   [p][d]
//   s=1: K' = val + pos_h + pos_w       [p][d]
//   s=2: Vt = val                       [d][p]  -- p PERMUTED within 32-groups
//        (slot = 8*qs + 4*t + r  <-  u = 16*t + 4*qs + r), so attn's PV can
//        consume P directly from the S^T C-layout registers (no LDS trip).
// ---------------------------------------------------------------------------
__global__ __launch_bounds__(256, 4) void qkv_proj(
    const short* __restrict__ xT, const short* __restrict__ Wb,
    const float* __restrict__ pos_h, const float* __restrict__ pos_w,
    short* __restrict__ Q, short* __restrict__ Kp, short* __restrict__ Vt)
{
    __shared__ __align__(1024) char smem[34816];
    short* As = (short*)smem;               // [128][64] content-swizzled
    short* Bs = As + 128 * 64;              // [128][64] content-swizzled
    short* vb = (short*)smem;               // [128][136] reused for V epilogue
    short* T  = (short*)smem;               // [128][128] reused for Q/K epilogue

    const int pt = blockIdx.x, ot = blockIdx.y, b = blockIdx.z;
    const int tid = threadIdx.x;
    const int wave = tid >> 6, lane = tid & 63;
    const int l16 = lane & 15, quad = lane >> 4;
    const int wm = (wave & 1) * 64, wn = (wave >> 1) * 64;
    const int o0 = ot * 128, p0 = pt * 128;

    const short* xb = xT + (size_t)b * HW * CIN;

    // DMA staging geometry: wave w covers rows [w*32, w*32+32); instr j covers
    // 8 rows (1024 B). Lane: row_local = j*8 + (lane>>3), phys chunk = lane&7.
    // Source chunk = phys ^ (row&7); row&7 == lane>>3 (j*8, w*32 are 0 mod 8).
    const int r8 = lane >> 3, c8 = lane & 7;
    const int sch = c8 ^ r8;                  // pre-swizzled source chunk
    const short* wsrc = Wb + (size_t)(o0 + wave * 32 + r8) * CIN + sch * 8;
    const short* xsrc = xb + (size_t)(p0 + wave * 32 + r8) * CIN + sch * 8;
    short* adst = As + wave * 2048;           // + j*512 shorts (= j*1024 B)
    short* bdst = Bs + wave * 2048;

    f32x4 acc[4][4];
    #pragma unroll
    for (int i = 0; i < 4; i++)
        #pragma unroll
        for (int j = 0; j < 4; j++)
            acc[i][j] = f32x4{0.f, 0.f, 0.f, 0.f};

    #pragma unroll 1
    for (int kc = 0; kc < CIN; kc += 64) {
        #pragma unroll
        for (int j = 0; j < 4; j++) {
            gload16(wsrc + kc + (size_t)(j * 8) * CIN, adst + j * 512);
            gload16(xsrc + kc + (size_t)(j * 8) * CIN, bdst + j * 512);
        }
        __syncthreads();   // drains vmcnt(0); TLP across 4 blocks hides it
        #pragma unroll
        for (int kk = 0; kk < 2; kk++) {
            s16x8 aF[4], bF[4];
            #pragma unroll
            for (int mi = 0; mi < 4; mi++)
                aF[mi] = *(const s16x8*)(As + (wm + mi * 16 + l16) * 64
                                         + (((kk * 4 + quad) ^ (l16 & 7)) * 8));
            #pragma unroll
            for (int ni = 0; ni < 4; ni++)
                bF[ni] = *(const s16x8*)(Bs + (wn + ni * 16 + l16) * 64
                                         + (((kk * 4 + quad) ^ (l16 & 7)) * 8));
            #pragma unroll
            for (int mi = 0; mi < 4; mi++)
                #pragma unroll
                for (int ni = 0; ni < 4; ni++)
                    acc[mi][ni] = __builtin_amdgcn_mfma_f32_16x16x32_bf16(
                        aF[mi], bF[ni], acc[mi][ni], 0, 0, 0);
        }
        __syncthreads();   // all reads done before next DMA overwrites
    }

    const int s = ot >> 2, h = ot & 3;
    const size_t bh = (size_t)(b * NH + h);

    if (s < 2) {
        // ---- stage output tile in LDS T[128][128], swizzle phys=chunk^(row&7)
        const float qs = 0.08838834764831845f * 1.4426950408889634f; // scale*log2e
        #pragma unroll
        for (int mi = 0; mi < 4; mi++) {
            int col = wm + mi * 16 + quad * 4;        // logical col (shorts)
            int chunk = col >> 3, sub = (quad & 1) * 4;
            #pragma unroll
            for (int ni = 0; ni < 4; ni++) {
                int row = wn + ni * 16 + l16;         // row&7 == l16&7
                f32x4 a = acc[mi][ni];
                s16x4 o4;
                if (s == 0) {
                    o4 = s16x4{ f2bf(a.x * qs), f2bf(a.y * qs),
                                f2bf(a.z * qs), f2bf(a.w * qs) };
                } else {
                    int p = p0 + row;
                    const float4 eh = *reinterpret_cast<const float4*>(pos_h + (p >> 5) * HD + col);
                    const float4 ew = *reinterpret_cast<const float4*>(pos_w + (p & 31) * HD + col);
                    o4 = s16x4{ f2bf(a.x + eh.x + ew.x), f2bf(a.y + eh.y + ew.y),
                                f2bf(a.z + eh.z + ew.z), f2bf(a.w + eh.w + ew.w) };
                }
                *(s16x4*)(T + row * 128 + ((chunk ^ (l16 & 7)) * 8 + sub)) = o4;
            }
        }
        __syncthreads();
        // ---- coalesced write-out: block region is contiguous 32 KB
        short* Ob = (s == 0 ? Q : Kp) + bh * (size_t)(HW * HD) + (size_t)p0 * HD;
        #pragma unroll
        for (int j = 0; j < 8; j++) {
            int row = j * 16 + (tid >> 4);            // row&7 == (tid>>4)&7
            int c16 = tid & 15;
            s16x8 v8 = *(const s16x8*)(T + row * 128 + ((c16 ^ ((tid >> 4) & 7)) * 8));
            *reinterpret_cast<s16x8*>(Ob + (size_t)row * HD + c16 * 8) = v8;
        }
    } else {
        __syncthreads();   // done with As/Bs before vb overlay
        #pragma unroll
        for (int mi = 0; mi < 4; mi++) {
            int d0 = wm + mi * 16 + quad * 4;
            #pragma unroll
            for (int ni = 0; ni < 4; ni++) {
                int p = wn + ni * 16 + l16;
                f32x4 a = acc[mi][ni];
                vb[(d0 + 0) * 136 + p] = f2bf(a.x);
                vb[(d0 + 1) * 136 + p] = f2bf(a.y);
                vb[(d0 + 2) * 136 + p] = f2bf(a.z);
                vb[(d0 + 3) * 136 + p] = f2bf(a.w);
            }
        }
        __syncthreads();
        short* Vb = Vt + bh * (size_t)(HD * HW);
        // coalesced write-out with key-permuted gather (verified R11): output
        // chunk c16 spans slots g*32 + 8qs..8qs+7 with g=c16>>2, qs=c16&3:
        //   slots 8qs..+3 <- u = g*32 + 4qs + r ; slots +4..+7 <- u + 16
        #pragma unroll
        for (int j = 0; j < 8; j++) {
            int d = j * 16 + (tid >> 4);
            int c16 = tid & 15;                    // output chunk (8 shorts)
            const short* row = vb + d * 136;
            int g = c16 >> 2, qs = c16 & 3;
            int base = g * 32 + qs * 4;
            s16x4 lo = *(const s16x4*)(row + base);        // t=0
            s16x4 hi = *(const s16x4*)(row + base + 16);   // t=1
            s16x8 v8 = { lo[0], lo[1], lo[2], lo[3],
                         hi[0], hi[1], hi[2], hi[3] };
            *reinterpret_cast<s16x8*>(Vb + (size_t)d * HW + p0 + c16 * 8) = v8;
        }
    }
}

// ---------------------------------------------------------------------------
// Fused attention (R5 verbatim -- best measured 46.6us; R8 no-LDS and R9
// hybrid both regressed: direct global loads feeding MFMA are latency-toxic
// at 8 waves/CU, and mixing consumed global loads after prefetch DMA couples
// them through the shared vmcnt counter). 256 thr = 4 waves x 32 Q-ROWS,
// kt = 64 keys x 16 iters. K/V DMA-staged, double-buffered, ONE barrier/iter.
// P NEVER TOUCHES LDS: V stored key-PERMUTED (qkv_proj) so S^T's C-layout
// regs are directly PV's A-frags. Bank conflicts = 0 (verified).
// Grid 512 (bh = flat&63: XCD-affine), 2 blocks/CU (66KB LDS).
// ---------------------------------------------------------------------------
__global__ __launch_bounds__(256, 2) void attn_fused(
    const short* __restrict__ Q, const short* __restrict__ Kp,
    const short* __restrict__ Vt, float* __restrict__ out)
{
    __shared__ __align__(1024) short Ks[2][64 * 128];   // [buf][key][d] swz: c^(key&15)
    __shared__ __align__(1024) short Vs[2][128 * 64];   // [buf][d][slot] swz: c^(d&7)

    const int flat = blockIdx.x;
    const int qt = flat >> 6;              // 0..7
    const int bh = flat & 63;              // XCD-affine: bh%8 == blockIdx%8
    const int tid = threadIdx.x;
    const int wave = tid >> 6, lane = tid & 63;
    const int l16 = lane & 15, quad = lane >> 4;

    const short* Qb = Q + (size_t)bh * (HW * HD);
    const short* Kb = Kp + (size_t)bh * (HW * HD);
    const short* Vb = Vt + (size_t)bh * (HD * HW);

    const int q0 = qt * 128 + wave * 32;

    // Q fragments (B-operand for S^T): this wave's 32 rows, K=128 -> 2x4 frags
    s16x8 bQ[2][4];
    #pragma unroll
    for (int nt = 0; nt < 2; nt++)
        #pragma unroll
        for (int kk = 0; kk < 4; kk++)
            bQ[nt][kk] = *(const s16x8*)(Qb + (size_t)(q0 + nt * 16 + l16) * HD
                                         + kk * 32 + quad * 8);

    s16x8 ones;
    #pragma unroll
    for (int j = 0; j < 8; j++) ones[j] = (short)0x3F80;   // bf16 1.0

    f32x4 Oacc[2][8];
    #pragma unroll
    for (int mt = 0; mt < 2; mt++)
        #pragma unroll
        for (int dt = 0; dt < 8; dt++)
            Oacc[mt][dt] = f32x4{0.f, 0.f, 0.f, 0.f};
    f32x4 lacc[2] = { f32x4{0.f, 0.f, 0.f, 0.f}, f32x4{0.f, 0.f, 0.f, 0.f} };

    // DMA staging geometry (32 KB/tile = 32 instrs of 1KB; 8 per wave):
    // K instr j: keys wave*16 + j*4 .. +4. lane: key = base + (lane>>4),
    //   phys chunk = lane&15, src chunk = (lane&15) ^ (key&15),
    //   key&15 = j*4 + (lane>>4)  (wave*16 == 0 mod 16).
    // V instr j: d = wave*32 + j*8 .. +8. lane: d = base + (lane>>3),
    //   phys chunk = lane&7, src chunk = (lane&7) ^ (lane>>3)  (d&7 == lane>>3).
    const int kRow = lane >> 4;            // 0..3
    const int vRow = lane >> 3;            // 0..7
    const int vSch = (lane & 7) ^ vRow;    // V source chunk (j-independent)

    #define STAGE(buf, tile)                                                  \
        do {                                                                  \
            _Pragma("unroll")                                                 \
            for (int j = 0; j < 4; j++) {                                     \
                int kkey = wave * 16 + j * 4 + kRow;                          \
                gload16(Kb + ((size_t)((tile) * 64 + kkey)) * HD              \
                           + (((lane & 15) ^ (j * 4 + kRow)) * 8),            \
                        &Ks[buf][(wave * 16 + j * 4) * 128] + lane * 8);      \
                int vd = wave * 32 + j * 8 + vRow;                            \
                gload16(Vb + (size_t)vd * HW + (tile) * 64 + vSch * 8,        \
                        &Vs[buf][(wave * 32 + j * 8) * 64] + lane * 8);       \
            }                                                                 \
        } while (0)

    STAGE(0, 0);           // tile 0 -> buf0 (vmcnt drained by barrier below)
    __syncthreads();

    #pragma unroll 1
    for (int kt = 0; kt < 16; kt++) {
        const int cur = kt & 1, nxt = cur ^ 1;
        const short* ks = Ks[cur];
        const short* vs = Vs[cur];

        // issue DMA for tile kt+1 into nxt (overlaps this iter's compute;
        // nxt's last readers finished at iter kt-1, ordered by its barrier)
        STAGE(nxt, (kt + 1) & 15);   // wrap at end: harmless L2-hot reload

        // ---- S^T: 64 keys x 32 qrows (aK shared across both q-tiles)
        f32x4 c[4][2];
        __builtin_amdgcn_s_setprio(1);
        #pragma unroll
        for (int mtp = 0; mtp < 4; mtp++) {
            s16x8 aK[4];
            #pragma unroll
            for (int kk = 0; kk < 4; kk++)
                aK[kk] = *(const s16x8*)(ks + (mtp * 16 + l16) * 128
                                         + (((kk * 4 + quad) ^ l16) * 8));
            c[mtp][0] = f32x4{0.f, 0.f, 0.f, 0.f};
            c[mtp][1] = f32x4{0.f, 0.f, 0.f, 0.f};
            #pragma unroll
            for (int kk = 0; kk < 4; kk++) {
                c[mtp][0] = __builtin_amdgcn_mfma_f32_16x16x32_bf16(
                    aK[kk], bQ[0][kk], c[mtp][0], 0, 0, 0);
                c[mtp][1] = __builtin_amdgcn_mfma_f32_16x16x32_bf16(
                    aK[kk], bQ[1][kk], c[mtp][1], 0, 0, 0);
            }
        }
        __builtin_amdgcn_s_setprio(0);

        // ---- P = exp2(S') packed ENTIRELY in registers (V rows permuted to
        //      match the C-layout keys each lane holds). Two 32-key halves.
        #pragma unroll
        for (int h = 0; h < 2; h++) {
            s16x8 aP[2];
            #pragma unroll
            for (int mt = 0; mt < 2; mt++) {
                f32x4 e0 = c[2 * h][mt], e1 = c[2 * h + 1][mt];
                aP[mt] = s16x8{
                    f2bf(__builtin_amdgcn_exp2f(e0[0])),
                    f2bf(__builtin_amdgcn_exp2f(e0[1])),
                    f2bf(__builtin_amdgcn_exp2f(e0[2])),
                    f2bf(__builtin_amdgcn_exp2f(e0[3])),
                    f2bf(__builtin_amdgcn_exp2f(e1[0])),
                    f2bf(__builtin_amdgcn_exp2f(e1[1])),
                    f2bf(__builtin_amdgcn_exp2f(e1[2])),
                    f2bf(__builtin_amdgcn_exp2f(e1[3])) };
            }

            __builtin_amdgcn_s_setprio(1);
            #pragma unroll
            for (int mt = 0; mt < 2; mt++)
                lacc[mt] = __builtin_amdgcn_mfma_f32_16x16x32_bf16(
                    aP[mt], ones, lacc[mt], 0, 0, 0);

            #pragma unroll
            for (int dt = 0; dt < 8; dt++) {
                s16x8 bV = *(const s16x8*)(vs + (dt * 16 + l16) * 64
                                           + (((h * 4 + quad) ^ (l16 & 7)) * 8));
                #pragma unroll
                for (int mt = 0; mt < 2; mt++)
                    Oacc[mt][dt] = __builtin_amdgcn_mfma_f32_16x16x32_bf16(
                        aP[mt], bV, Oacc[mt][dt], 0, 0, 0);
            }
            __builtin_amdgcn_s_setprio(0);
        }
        __syncthreads();   // drains DMA (nxt ready) + orders cur reads
    }
    #undef STAGE

    // epilogue: O/l, stored transposed -> out[b][h][d][p] FP32
    float* ob = out + (size_t)bh * (HD * HW);
    #pragma unroll
    for (int mt = 0; mt < 2; mt++) {
        float inv[4];
        #pragma unroll
        for (int r = 0; r < 4; r++) inv[r] = __builtin_amdgcn_rcpf(lacc[mt][r]);
        int prow = q0 + mt * 16 + quad * 4;
        #pragma unroll
        for (int dt = 0; dt < 8; dt++) {
            int d = dt * 16 + l16;
            f32x4 o = Oacc[mt][dt];
            float4 o4 = { o[0] * inv[0], o[1] * inv[1],
                          o[2] * inv[2], o[3] * inv[3] };
            *reinterpret_cast<float4*>(ob + (size_t)d * HW + prow) = o4;
        }
    }
}

// ---------------------------------------------------------------------------
extern "C" void kernel_launch(void* const* d_in, const int* in_sizes, int n_in,
                              void* d_out, int out_size, void* d_ws, size_t ws_size,
                              hipStream_t stream) {
    const float* x  = (const float*)d_in[0];
    const float* w  = (const float*)d_in[1];
    const float* ph = (const float*)d_in[2];
    const float* pw = (const float*)d_in[3];

    const size_t BHPD = (size_t)NB * NH * HW * HD;   // 8,388,608 elems
    short* Q    = (short*)d_ws;
    short* Kp   = Q + BHPD;
    short* Vt   = Kp + BHPD;
    short* xT   = Vt + BHPD;
    short* Wb   = xT + (size_t)NB * HW * CIN;
    float* outp = (float*)d_out;

    prep_xw<<<dim3(NB * 16 * 32 + 768), 256, 0, stream>>>(x, w, xT, Wb);
    qkv_proj<<<dim3(8, 12, NB), 256, 0, stream>>>(xT, Wb, ph, pw, Q, Kp, Vt);
    attn_fused<<<dim3(512), 256, 0, stream>>>(Q, Kp, Vt, outp);
}

// Round 13
// 159.179 us; speedup vs baseline: 1.6007x; 1.0200x over previous
//
#include <hip/hip_runtime.h>

#define NB 16
#define NH 4
#define HD 128
#define HW 1024
#define CIN 512

typedef short s16x8 __attribute__((ext_vector_type(8)));
typedef short s16x4 __attribute__((ext_vector_type(4)));
typedef float f32x4 __attribute__((ext_vector_type(4)));

static __device__ __forceinline__ short f2bf(float f) {
    union { float f; unsigned u; } v; v.f = f;
    unsigned r = v.u + 0x7fffu + ((v.u >> 16) & 1u);   // round-to-nearest-even
    return (short)(r >> 16);
}

// async global->LDS DMA, 16B per lane. LDS dest is wave-uniform base + lane*16
// (linear); global src is per-lane (carries the XOR swizzle).
static __device__ __forceinline__ void gload16(const short* g, short* l) {
    __builtin_amdgcn_global_load_lds(
        (const __attribute__((address_space(1))) unsigned int*)g,
        (__attribute__((address_space(3))) unsigned int*)l, 16, 0, 0);
}

// ---------------------------------------------------------------------------
// prep: x[b][c][p] fp32 -> xT[b][p][c] bf16 (32x32 LDS tile transpose)
//       W[o][c]   fp32 -> Wb bf16 (elementwise)
// R13: global sides vectorized (G13). Transpose read: one float4/lane
// (was 4 scalar fp32); LDS row stride 36 (144B = 16B-aligned rows -> b128
// writes). W part: 2 float4 -> s16x8 (16B/lane both sides), 384 blocks.
// Output mapping bit-identical to R12.
// ---------------------------------------------------------------------------
__global__ __launch_bounds__(256) void prep_xw(
    const float* __restrict__ x, const float* __restrict__ w,
    short* __restrict__ xT, short* __restrict__ Wb)
{
    int blk = blockIdx.x;
    if (blk < NB * 16 * 32) {                  // 8192 transpose tiles
        int b = blk >> 9, rem = blk & 511;
        int ct = rem >> 5, pt = rem & 31;      // 16 c-tiles x 32 p-tiles
        __shared__ float tile[32][36];         // stride 36: 16B-aligned rows
        int t = threadIdx.x;
        int c = t >> 3, px = (t & 7) * 4;      // 32 rows x 8 lanes x float4
        const float* xb = x + ((size_t)b * CIN + ct * 32) * HW + pt * 32;
        float4 f4 = *reinterpret_cast<const float4*>(xb + (size_t)c * HW + px);
        *reinterpret_cast<float4*>(&tile[c][px]) = f4;
        __syncthreads();
        int p = t >> 3, cq = t & 7;
        short* xo = xT + ((size_t)b * HW + pt * 32 + p) * CIN + ct * 32 + cq * 4;
        s16x4 o4 = { f2bf(tile[cq * 4 + 0][p]), f2bf(tile[cq * 4 + 1][p]),
                     f2bf(tile[cq * 4 + 2][p]), f2bf(tile[cq * 4 + 3][p]) };
        *reinterpret_cast<s16x4*>(xo) = o4;
    } else {
        int wb = blk - NB * 16 * 32;           // 0..383, 2048 elems each
        size_t base = (size_t)wb * 2048 + threadIdx.x * 8;
        const float4 v0 = *reinterpret_cast<const float4*>(w + base);
        const float4 v1 = *reinterpret_cast<const float4*>(w + base + 4);
        s16x8 o8 = { f2bf(v0.x), f2bf(v0.y), f2bf(v0.z), f2bf(v0.w),
                     f2bf(v1.x), f2bf(v1.y), f2bf(v1.z), f2bf(v1.w) };
        *reinterpret_cast<s16x8*>(Wb + base) = o8;
    }
}

// ---------------------------------------------------------------------------
// qkv projection GEMM, BK=64. R12 (verified: occupancy was the binder):
// single-buffered m97 loop at __launch_bounds__(256,4): 4 blocks/CU (139KB
// LDS, VGPR 88). Per-step DMA drain at the barrier hidden by TLP across 4
// co-resident blocks (m114). Coalesced epilogues (R11, verified).
// Content keeps the 16B-chunk XOR swizzle (phys = c ^ (row&7)) via
// PRE-SWIZZLED per-lane global source + linear LDS dest (m173 pattern).
//   s=0: Q = val * (128^-0.5 * log2e)   [p][d]
//   s=1: K' = val + pos_h + pos_w       [p][d]
//   s=2: Vt = val                       [d][p]  -- p PERMUTED within 32-groups
//        (slot = 8*qs + 4*t + r  <-  u = 16*t + 4*qs + r), so attn's PV can
//        consume P directly from the S^T C-layout registers (no LDS trip).
// ---------------------------------------------------------------------------
__global__ __launch_bounds__(256, 4) void qkv_proj(
    const short* __restrict__ xT, const short* __restrict__ Wb,
    const float* __restrict__ pos_h, const float* __restrict__ pos_w,
    short* __restrict__ Q, short* __restrict__ Kp, short* __restrict__ Vt)
{
    __shared__ __align__(1024) char smem[34816];
    short* As = (short*)smem;               // [128][64] content-swizzled
    short* Bs = As + 128 * 64;              // [128][64] content-swizzled
    short* vb = (short*)smem;               // [128][136] reused for V epilogue
    short* T  = (short*)smem;               // [128][128] reused for Q/K epilogue

    const int pt = blockIdx.x, ot = blockIdx.y, b = blockIdx.z;
    const int tid = threadIdx.x;
    const int wave = tid >> 6, lane = tid & 63;
    const int l16 = lane & 15, quad = lane >> 4;
    const int wm = (wave & 1) * 64, wn = (wave >> 1) * 64;
    const int o0 = ot * 128, p0 = pt * 128;

    const short* xb = xT + (size_t)b * HW * CIN;

    // DMA staging geometry: wave w covers rows [w*32, w*32+32); instr j covers
    // 8 rows (1024 B). Lane: row_local = j*8 + (lane>>3), phys chunk = lane&7.
    // Source chunk = phys ^ (row&7); row&7 == lane>>3 (j*8, w*32 are 0 mod 8).
    const int r8 = lane >> 3, c8 = lane & 7;
    const int sch = c8 ^ r8;                  // pre-swizzled source chunk
    const short* wsrc = Wb + (size_t)(o0 + wave * 32 + r8) * CIN + sch * 8;
    const short* xsrc = xb + (size_t)(p0 + wave * 32 + r8) * CIN + sch * 8;
    short* adst = As + wave * 2048;           // + j*512 shorts (= j*1024 B)
    short* bdst = Bs + wave * 2048;

    f32x4 acc[4][4];
    #pragma unroll
    for (int i = 0; i < 4; i++)
        #pragma unroll
        for (int j = 0; j < 4; j++)
            acc[i][j] = f32x4{0.f, 0.f, 0.f, 0.f};

    #pragma unroll 1
    for (int kc = 0; kc < CIN; kc += 64) {
        #pragma unroll
        for (int j = 0; j < 4; j++) {
            gload16(wsrc + kc + (size_t)(j * 8) * CIN, adst + j * 512);
            gload16(xsrc + kc + (size_t)(j * 8) * CIN, bdst + j * 512);
        }
        __syncthreads();   // drains vmcnt(0); TLP across 4 blocks hides it
        #pragma unroll
        for (int kk = 0; kk < 2; kk++) {
            s16x8 aF[4], bF[4];
            #pragma unroll
            for (int mi = 0; mi < 4; mi++)
                aF[mi] = *(const s16x8*)(As + (wm + mi * 16 + l16) * 64
                                         + (((kk * 4 + quad) ^ (l16 & 7)) * 8));
            #pragma unroll
            for (int ni = 0; ni < 4; ni++)
                bF[ni] = *(const s16x8*)(Bs + (wn + ni * 16 + l16) * 64
                                         + (((kk * 4 + quad) ^ (l16 & 7)) * 8));
            #pragma unroll
            for (int mi = 0; mi < 4; mi++)
                #pragma unroll
                for (int ni = 0; ni < 4; ni++)
                    acc[mi][ni] = __builtin_amdgcn_mfma_f32_16x16x32_bf16(
                        aF[mi], bF[ni], acc[mi][ni], 0, 0, 0);
        }
        __syncthreads();   // all reads done before next DMA overwrites
    }

    const int s = ot >> 2, h = ot & 3;
    const size_t bh = (size_t)(b * NH + h);

    if (s < 2) {
        // ---- stage output tile in LDS T[128][128], swizzle phys=chunk^(row&7)
        const float qs = 0.08838834764831845f * 1.4426950408889634f; // scale*log2e
        #pragma unroll
        for (int mi = 0; mi < 4; mi++) {
            int col = wm + mi * 16 + quad * 4;        // logical col (shorts)
            int chunk = col >> 3, sub = (quad & 1) * 4;
            #pragma unroll
            for (int ni = 0; ni < 4; ni++) {
                int row = wn + ni * 16 + l16;         // row&7 == l16&7
                f32x4 a = acc[mi][ni];
                s16x4 o4;
                if (s == 0) {
                    o4 = s16x4{ f2bf(a.x * qs), f2bf(a.y * qs),
                                f2bf(a.z * qs), f2bf(a.w * qs) };
                } else {
                    int p = p0 + row;
                    const float4 eh = *reinterpret_cast<const float4*>(pos_h + (p >> 5) * HD + col);
                    const float4 ew = *reinterpret_cast<const float4*>(pos_w + (p & 31) * HD + col);
                    o4 = s16x4{ f2bf(a.x + eh.x + ew.x), f2bf(a.y + eh.y + ew.y),
                                f2bf(a.z + eh.z + ew.z), f2bf(a.w + eh.w + ew.w) };
                }
                *(s16x4*)(T + row * 128 + ((chunk ^ (l16 & 7)) * 8 + sub)) = o4;
            }
        }
        __syncthreads();
        // ---- coalesced write-out: block region is contiguous 32 KB
        short* Ob = (s == 0 ? Q : Kp) + bh * (size_t)(HW * HD) + (size_t)p0 * HD;
        #pragma unroll
        for (int j = 0; j < 8; j++) {
            int row = j * 16 + (tid >> 4);            // row&7 == (tid>>4)&7
            int c16 = tid & 15;
            s16x8 v8 = *(const s16x8*)(T + row * 128 + ((c16 ^ ((tid >> 4) & 7)) * 8));
            *reinterpret_cast<s16x8*>(Ob + (size_t)row * HD + c16 * 8) = v8;
        }
    } else {
        __syncthreads();   // done with As/Bs before vb overlay
        #pragma unroll
        for (int mi = 0; mi < 4; mi++) {
            int d0 = wm + mi * 16 + quad * 4;
            #pragma unroll
            for (int ni = 0; ni < 4; ni++) {
                int p = wn + ni * 16 + l16;
                f32x4 a = acc[mi][ni];
                vb[(d0 + 0) * 136 + p] = f2bf(a.x);
                vb[(d0 + 1) * 136 + p] = f2bf(a.y);
                vb[(d0 + 2) * 136 + p] = f2bf(a.z);
                vb[(d0 + 3) * 136 + p] = f2bf(a.w);
            }
        }
        __syncthreads();
        short* Vb = Vt + bh * (size_t)(HD * HW);
        // coalesced write-out with key-permuted gather (verified R11): output
        // chunk c16 spans slots g*32 + 8qs..8qs+7 with g=c16>>2, qs=c16&3:
        //   slots 8qs..+3 <- u = g*32 + 4qs + r ; slots +4..+7 <- u + 16
        #pragma unroll
        for (int j = 0; j < 8; j++) {
            int d = j * 16 + (tid >> 4);
            int c16 = tid & 15;                    // output chunk (8 shorts)
            const short* row = vb + d * 136;
            int g = c16 >> 2, qs = c16 & 3;
            int base = g * 32 + qs * 4;
            s16x4 lo = *(const s16x4*)(row + base);        // t=0
            s16x4 hi = *(const s16x4*)(row + base + 16);   // t=1
            s16x8 v8 = { lo[0], lo[1], lo[2], lo[3],
                         hi[0], hi[1], hi[2], hi[3] };
            *reinterpret_cast<s16x8*>(Vb + (size_t)d * HW + p0 + c16 * 8) = v8;
        }
    }
}

// ---------------------------------------------------------------------------
// Fused attention (R5 verbatim -- best measured 46.6us; R8 no-LDS and R9
// hybrid both regressed: direct global loads feeding MFMA are latency-toxic
// at 8 waves/CU, and mixing consumed global loads after prefetch DMA couples
// them through the shared vmcnt counter). 256 thr = 4 waves x 32 Q-ROWS,
// kt = 64 keys x 16 iters. K/V DMA-staged, double-buffered, ONE barrier/iter.
// P NEVER TOUCHES LDS: V stored key-PERMUTED (qkv_proj) so S^T's C-layout
// regs are directly PV's A-frags. Bank conflicts = 0 (verified).
// Grid 512 (bh = flat&63: XCD-affine), 2 blocks/CU (66KB LDS).
// ---------------------------------------------------------------------------
__global__ __launch_bounds__(256, 2) void attn_fused(
    const short* __restrict__ Q, const short* __restrict__ Kp,
    const short* __restrict__ Vt, float* __restrict__ out)
{
    __shared__ __align__(1024) short Ks[2][64 * 128];   // [buf][key][d] swz: c^(key&15)
    __shared__ __align__(1024) short Vs[2][128 * 64];   // [buf][d][slot] swz: c^(d&7)

    const int flat = blockIdx.x;
    const int qt = flat >> 6;              // 0..7
    const int bh = flat & 63;              // XCD-affine: bh%8 == blockIdx%8
    const int tid = threadIdx.x;
    const int wave = tid >> 6, lane = tid & 63;
    const int l16 = lane & 15, quad = lane >> 4;

    const short* Qb = Q + (size_t)bh * (HW * HD);
    const short* Kb = Kp + (size_t)bh * (HW * HD);
    const short* Vb = Vt + (size_t)bh * (HD * HW);

    const int q0 = qt * 128 + wave * 32;

    // Q fragments (B-operand for S^T): this wave's 32 rows, K=128 -> 2x4 frags
    s16x8 bQ[2][4];
    #pragma unroll
    for (int nt = 0; nt < 2; nt++)
        #pragma unroll
        for (int kk = 0; kk < 4; kk++)
            bQ[nt][kk] = *(const s16x8*)(Qb + (size_t)(q0 + nt * 16 + l16) * HD
                                         + kk * 32 + quad * 8);

    s16x8 ones;
    #pragma unroll
    for (int j = 0; j < 8; j++) ones[j] = (short)0x3F80;   // bf16 1.0

    f32x4 Oacc[2][8];
    #pragma unroll
    for (int mt = 0; mt < 2; mt++)
        #pragma unroll
        for (int dt = 0; dt < 8; dt++)
            Oacc[mt][dt] = f32x4{0.f, 0.f, 0.f, 0.f};
    f32x4 lacc[2] = { f32x4{0.f, 0.f, 0.f, 0.f}, f32x4{0.f, 0.f, 0.f, 0.f} };

    // DMA staging geometry (32 KB/tile = 32 instrs of 1KB; 8 per wave):
    // K instr j: keys wave*16 + j*4 .. +4. lane: key = base + (lane>>4),
    //   phys chunk = lane&15, src chunk = (lane&15) ^ (key&15),
    //   key&15 = j*4 + (lane>>4)  (wave*16 == 0 mod 16).
    // V instr j: d = wave*32 + j*8 .. +8. lane: d = base + (lane>>3),
    //   phys chunk = lane&7, src chunk = (lane&7) ^ (lane>>3)  (d&7 == lane>>3).
    const int kRow = lane >> 4;            // 0..3
    const int vRow = lane >> 3;            // 0..7
    const int vSch = (lane & 7) ^ vRow;    // V source chunk (j-independent)

    #define STAGE(buf, tile)                                                  \
        do {                                                                  \
            _Pragma("unroll")                                                 \
            for (int j = 0; j < 4; j++) {                                     \
                int kkey = wave * 16 + j * 4 + kRow;                          \
                gload16(Kb + ((size_t)((tile) * 64 + kkey)) * HD              \
                           + (((lane & 15) ^ (j * 4 + kRow)) * 8),            \
                        &Ks[buf][(wave * 16 + j * 4) * 128] + lane * 8);      \
                int vd = wave * 32 + j * 8 + vRow;                            \
                gload16(Vb + (size_t)vd * HW + (tile) * 64 + vSch * 8,        \
                        &Vs[buf][(wave * 32 + j * 8) * 64] + lane * 8);       \
            }                                                                 \
        } while (0)

    STAGE(0, 0);           // tile 0 -> buf0 (vmcnt drained by barrier below)
    __syncthreads();

    #pragma unroll 1
    for (int kt = 0; kt < 16; kt++) {
        const int cur = kt & 1, nxt = cur ^ 1;
        const short* ks = Ks[cur];
        const short* vs = Vs[cur];

        // issue DMA for tile kt+1 into nxt (overlaps this iter's compute;
        // nxt's last readers finished at iter kt-1, ordered by its barrier)
        STAGE(nxt, (kt + 1) & 15);   // wrap at end: harmless L2-hot reload

        // ---- S^T: 64 keys x 32 qrows (aK shared across both q-tiles)
        f32x4 c[4][2];
        __builtin_amdgcn_s_setprio(1);
        #pragma unroll
        for (int mtp = 0; mtp < 4; mtp++) {
            s16x8 aK[4];
            #pragma unroll
            for (int kk = 0; kk < 4; kk++)
                aK[kk] = *(const s16x8*)(ks + (mtp * 16 + l16) * 128
                                         + (((kk * 4 + quad) ^ l16) * 8));
            c[mtp][0] = f32x4{0.f, 0.f, 0.f, 0.f};
            c[mtp][1] = f32x4{0.f, 0.f, 0.f, 0.f};
            #pragma unroll
            for (int kk = 0; kk < 4; kk++) {
                c[mtp][0] = __builtin_amdgcn_mfma_f32_16x16x32_bf16(
                    aK[kk], bQ[0][kk], c[mtp][0], 0, 0, 0);
                c[mtp][1] = __builtin_amdgcn_mfma_f32_16x16x32_bf16(
                    aK[kk], bQ[1][kk], c[mtp][1], 0, 0, 0);
            }
        }
        __builtin_amdgcn_s_setprio(0);

        // ---- P = exp2(S') packed ENTIRELY in registers (V rows permuted to
        //      match the C-layout keys each lane holds). Two 32-key halves.
        #pragma unroll
        for (int h = 0; h < 2; h++) {
            s16x8 aP[2];
            #pragma unroll
            for (int mt = 0; mt < 2; mt++) {
                f32x4 e0 = c[2 * h][mt], e1 = c[2 * h + 1][mt];
                aP[mt] = s16x8{
                    f2bf(__builtin_amdgcn_exp2f(e0[0])),
                    f2bf(__builtin_amdgcn_exp2f(e0[1])),
                    f2bf(__builtin_amdgcn_exp2f(e0[2])),
                    f2bf(__builtin_amdgcn_exp2f(e0[3])),
                    f2bf(__builtin_amdgcn_exp2f(e1[0])),
                    f2bf(__builtin_amdgcn_exp2f(e1[1])),
                    f2bf(__builtin_amdgcn_exp2f(e1[2])),
                    f2bf(__builtin_amdgcn_exp2f(e1[3])) };
            }

            __builtin_amdgcn_s_setprio(1);
            #pragma unroll
            for (int mt = 0; mt < 2; mt++)
                lacc[mt] = __builtin_amdgcn_mfma_f32_16x16x32_bf16(
                    aP[mt], ones, lacc[mt], 0, 0, 0);

            #pragma unroll
            for (int dt = 0; dt < 8; dt++) {
                s16x8 bV = *(const s16x8*)(vs + (dt * 16 + l16) * 64
                                           + (((h * 4 + quad) ^ (l16 & 7)) * 8));
                #pragma unroll
                for (int mt = 0; mt < 2; mt++)
                    Oacc[mt][dt] = __builtin_amdgcn_mfma_f32_16x16x32_bf16(
                        aP[mt], bV, Oacc[mt][dt], 0, 0, 0);
            }
            __builtin_amdgcn_s_setprio(0);
        }
        __syncthreads();   // drains DMA (nxt ready) + orders cur reads
    }
    #undef STAGE

    // epilogue: O/l, stored transposed -> out[b][h][d][p] FP32
    float* ob = out + (size_t)bh * (HD * HW);
    #pragma unroll
    for (int mt = 0; mt < 2; mt++) {
        float inv[4];
        #pragma unroll
        for (int r = 0; r < 4; r++) inv[r] = __builtin_amdgcn_rcpf(lacc[mt][r]);
        int prow = q0 + mt * 16 + quad * 4;
        #pragma unroll
        for (int dt = 0; dt < 8; dt++) {
            int d = dt * 16 + l16;
            f32x4 o = Oacc[mt][dt];
            float4 o4 = { o[0] * inv[0], o[1] * inv[1],
                          o[2] * inv[2], o[3] * inv[3] };
            *reinterpret_cast<float4*>(ob + (size_t)d * HW + prow) = o4;
        }
    }
}

// ---------------------------------------------------------------------------
extern "C" void kernel_launch(void* const* d_in, const int* in_sizes, int n_in,
                              void* d_out, int out_size, void* d_ws, size_t ws_size,
                              hipStream_t stream) {
    const float* x  = (const float*)d_in[0];
    const float* w  = (const float*)d_in[1];
    const float* ph = (const float*)d_in[2];
    const float* pw = (const float*)d_in[3];

    const size_t BHPD = (size_t)NB * NH * HW * HD;   // 8,388,608 elems
    short* Q    = (short*)d_ws;
    short* Kp   = Q + BHPD;
    short* Vt   = Kp + BHPD;
    short* xT   = Vt + BHPD;
    short* Wb   = xT + (size_t)NB * HW * CIN;
    float* outp = (float*)d_out;

    prep_xw<<<dim3(NB * 16 * 32 + 384), 256, 0, stream>>>(x, w, xT, Wb);
    qkv_proj<<<dim3(8, 12, NB), 256, 0, stream>>>(xT, Wb, ph, pw, Q, Kp, Vt);
    attn_fused<<<dim3(512), 256, 0, stream>>>(Q, Kp, Vt, outp);
}